// Round 2
// baseline (58645.538 us; speedup 1.0000x reference)
//
#include <hip/hip_runtime.h>
#include <math.h>

#define F 8
#define H 512
#define BB 256      // batch
#define T_IN 336
#define T_OUT 96
#define D_OUT 2
#define NG 8        // independent groups (≈ XCDs)
#define WPG 32      // workgroups per group
#define ROWS 32     // batch rows per group
#define NT 512      // threads per block
#define LSTR 1028   // LDS row stride in dwords (1024 + 4; ≡4 mod 32 → conflict-free b128)

struct Args {
  const float *src;
  const float *eWih0, *eWhh0, *eb0, *eWih1, *eWhh1, *eb1;
  const float *dWih0, *dWhh0, *db0, *dWih1, *dWhh1, *db1;
  const float *fcW, *fcb, *pW, *pb;
  float *out;      // [BB][T_OUT][D_OUT]
  float *h0;       // [2][H][BB]  (transposed: k-major)
  float *h1;       // [2][H][BB]
  unsigned *cnt;   // [NG] spaced 32 uints apart
};

__device__ __forceinline__ float sigm(float x) { return 1.f / (1.f + __expf(-x)); }
__device__ __forceinline__ float tanh_f(float x) {
  float e = __expf(-2.f * fabsf(x));
  float r = (1.f - e) / (1.f + e);
  return copysignf(r, x);
}

// group barrier: monotonic counter, device-scope.
// __threadfence() by ALL threads (release: h-state global writes visible agent-wide)
// before the counter bump; acquire fence after the spin.
__device__ __forceinline__ void gbar(unsigned* cnt, unsigned& bar) {
  bar += WPG;
  __threadfence();
  __syncthreads();
  if (threadIdx.x == 0) {
    __hip_atomic_fetch_add(cnt, 1u, __ATOMIC_RELAXED, __HIP_MEMORY_SCOPE_AGENT);
    long guard = 0;
    while (__hip_atomic_load(cnt, __ATOMIC_RELAXED, __HIP_MEMORY_SCOPE_AGENT) < bar) {
      __builtin_amdgcn_s_sleep(1);
      if (++guard > (1L << 22)) break;  // safety valve (pathological non-residency)
    }
    __threadfence();
  }
  __syncthreads();
}

// stage 512 k-rows of a transposed [H][BB] state into LDS cols [off, off+512)
__device__ __forceinline__ void stage_half(float* xcat, const float* hg, int grp, int tid, int off) {
  const int b = tid & 31, kc = tid >> 5;   // kc in 0..15
  const float* s = hg + grp * ROWS + b + (size_t)(kc * 32) * BB;
  float* d = xcat + b * LSTR + off + kc * 32;
  #pragma unroll
  for (int j = 0; j < 8; ++j) {
    float4 v;
    v.x = s[0]; v.y = s[BB]; v.z = s[2 * BB]; v.w = s[3 * BB];
    s += 4 * BB;
    *(float4*)d = v;
    d += 4;
  }
}

// acc 4 gate dot-products over K=512: weights broadcast across lanes, h from LDS
__device__ __forceinline__ void mac512(const float* __restrict__ hrow,
    const float* __restrict__ wi, const float* __restrict__ wf,
    const float* __restrict__ wg, const float* __restrict__ wo,
    float& ai, float& af, float& ag, float& ao) {
  #pragma unroll 2
  for (int k = 0; k < H; k += 4) {
    float4 hv = *(const float4*)(hrow + k);
    float4 vi = *(const float4*)(wi + k);
    float4 vf = *(const float4*)(wf + k);
    float4 vg = *(const float4*)(wg + k);
    float4 vo = *(const float4*)(wo + k);
    ai = fmaf(hv.x, vi.x, ai); ai = fmaf(hv.y, vi.y, ai); ai = fmaf(hv.z, vi.z, ai); ai = fmaf(hv.w, vi.w, ai);
    af = fmaf(hv.x, vf.x, af); af = fmaf(hv.y, vf.y, af); af = fmaf(hv.z, vf.z, af); af = fmaf(hv.w, vf.w, af);
    ag = fmaf(hv.x, vg.x, ag); ag = fmaf(hv.y, vg.y, ag); ag = fmaf(hv.z, vg.z, ag); ag = fmaf(hv.w, vg.w, ag);
    ao = fmaf(hv.x, vo.x, ao); ao = fmaf(hv.y, vo.y, ao); ao = fmaf(hv.z, vo.z, ao); ao = fmaf(hv.w, vo.w, ao);
  }
}

__global__ __launch_bounds__(NT) void forecast_kernel(Args a) {
  extern __shared__ float smem[];
  float* xcat   = smem;                    // [ROWS][LSTR]  h-cat staging
  float* p_part = xcat + ROWS * LSTR;      // [NT] fc partials
  float* p_lds  = p_part + NT;             // [ROWS*2] pred
  float* x_lds  = p_lds + 64;              // [ROWS*9] decoder x (stride 9)

  const int tid = threadIdx.x;
  const int grp = blockIdx.x & 7;
  const int w   = blockIdx.x >> 3;         // 0..31
  const int b   = tid & 31;                // local batch row
  const int u   = tid >> 5;                // 0..15 unit within WG slice
  const int row = grp * ROWS + b;          // global batch row
  const int uu  = w * 16 + u;              // hidden unit
  unsigned* cnt = a.cnt + grp * 32;
  unsigned bar = 0;

  float c0 = 0.f, c1 = 0.f;

  // ---------------- encoder (layer0/layer1 pipelined) ----------------
  for (int t = 0; t <= T_IN; ++t) {
    const int pr = t & 1, pw = pr ^ 1;
    stage_half(xcat, a.h0 + (size_t)pr * H * BB, grp, tid, 0);
    stage_half(xcat, a.h1 + (size_t)pr * H * BB, grp, tid, 512);
    __syncthreads();
    float h0n = 0.f, h1n = 0.f;
    if (t < T_IN) {  // layer0 step t
      float ai = a.eb0[uu], af = a.eb0[512 + uu], ag = a.eb0[1024 + uu], ao = a.eb0[1536 + uu];
      const float* sr = a.src + (size_t)row * (T_IN * F) + t * F;
      float4 s0 = *(const float4*)sr;
      float4 s1 = *(const float4*)(sr + 4);
      float xv[8] = {s0.x, s0.y, s0.z, s0.w, s1.x, s1.y, s1.z, s1.w};
      const float* w0 = a.eWih0 + (size_t)uu * F;
      const float* w1 = a.eWih0 + (size_t)(512 + uu) * F;
      const float* w2 = a.eWih0 + (size_t)(1024 + uu) * F;
      const float* w3 = a.eWih0 + (size_t)(1536 + uu) * F;
      #pragma unroll
      for (int k = 0; k < F; ++k) {
        ai = fmaf(xv[k], w0[k], ai); af = fmaf(xv[k], w1[k], af);
        ag = fmaf(xv[k], w2[k], ag); ao = fmaf(xv[k], w3[k], ao);
      }
      mac512(xcat + b * LSTR,
             a.eWhh0 + (size_t)uu * H, a.eWhh0 + (size_t)(512 + uu) * H,
             a.eWhh0 + (size_t)(1024 + uu) * H, a.eWhh0 + (size_t)(1536 + uu) * H,
             ai, af, ag, ao);
      c0 = sigm(af) * c0 + sigm(ai) * tanh_f(ag);
      h0n = sigm(ao) * tanh_f(c0);
    }
    if (t >= 1) {  // layer1 step t-1
      float ai = a.eb1[uu], af = a.eb1[512 + uu], ag = a.eb1[1024 + uu], ao = a.eb1[1536 + uu];
      mac512(xcat + b * LSTR,
             a.eWih1 + (size_t)uu * H, a.eWih1 + (size_t)(512 + uu) * H,
             a.eWih1 + (size_t)(1024 + uu) * H, a.eWih1 + (size_t)(1536 + uu) * H,
             ai, af, ag, ao);
      mac512(xcat + b * LSTR + 512,
             a.eWhh1 + (size_t)uu * H, a.eWhh1 + (size_t)(512 + uu) * H,
             a.eWhh1 + (size_t)(1024 + uu) * H, a.eWhh1 + (size_t)(1536 + uu) * H,
             ai, af, ag, ao);
      c1 = sigm(af) * c1 + sigm(ai) * tanh_f(ag);
      h1n = sigm(ao) * tanh_f(c1);
    }
    if (t < T_IN) a.h0[(size_t)pw * H * BB + (size_t)uu * BB + row] = h0n;
    if (t >= 1)   a.h1[(size_t)pw * H * BB + (size_t)uu * BB + row] = h1n;
    gbar(cnt, bar);
  }
  // encoder finals: h0 in a.h0[0], h1 in a.h1[1]

  // ---------------- decoder ----------------
  for (int t = 0; t < T_OUT; ++t) {
    const int pA = t & 1;
    // phase A: stage h0(t-1), h1(t-1)
    stage_half(xcat, a.h0 + (size_t)pA * H * BB, grp, tid, 0);
    stage_half(xcat, a.h1 + (size_t)(pA ^ 1) * H * BB, grp, tid, 512);
    __syncthreads();
    {  // fc partials: pred(t-1) = h1(t-1) @ fcW^T + fcb
      const int bb = tid & 31, dd = (tid >> 5) & 1, ks = tid >> 6;
      const float* hr = xcat + bb * LSTR + 512 + ks * 64;
      const float* wr = a.fcW + dd * H + ks * 64;
      float s = 0.f;
      #pragma unroll 4
      for (int k = 0; k < 64; k += 4) {
        float4 hv = *(const float4*)(hr + k);
        float4 wv = *(const float4*)(wr + k);
        s = fmaf(hv.x, wv.x, s); s = fmaf(hv.y, wv.y, s);
        s = fmaf(hv.z, wv.z, s); s = fmaf(hv.w, wv.w, s);
      }
      p_part[tid] = s;
    }
    __syncthreads();
    if (tid < 64) {
      const int bb = tid & 31, dd = tid >> 5;
      float s = a.fcb[dd];
      #pragma unroll
      for (int ks = 0; ks < 8; ++ks) s += p_part[(ks << 6) + (dd << 5) + bb];
      if (t == 0) s = a.src[(size_t)(grp * ROWS + bb) * (T_IN * F) + 335 * F + dd * 2];  // pred0 = src[:,-1,[0,2]]
      p_lds[bb * 2 + dd] = s;
      if (w == 0 && t > 0)
        a.out[(size_t)(grp * ROWS + bb) * (T_OUT * D_OUT) + (size_t)(t - 1) * D_OUT + dd] = s;
    }
    __syncthreads();
    if (tid < 256) {  // x = pred @ pW^T + pb
      const int bb = tid & 31, j = tid >> 5;
      x_lds[bb * 9 + j] = a.pb[j] + p_lds[bb * 2] * a.pW[j * 2] + p_lds[bb * 2 + 1] * a.pW[j * 2 + 1];
    }
    __syncthreads();
    {  // gates0
      float ai = a.db0[uu], af = a.db0[512 + uu], ag = a.db0[1024 + uu], ao = a.db0[1536 + uu];
      const float* xr = x_lds + b * 9;
      const float* w0 = a.dWih0 + (size_t)uu * F;
      const float* w1 = a.dWih0 + (size_t)(512 + uu) * F;
      const float* w2 = a.dWih0 + (size_t)(1024 + uu) * F;
      const float* w3 = a.dWih0 + (size_t)(1536 + uu) * F;
      #pragma unroll
      for (int k = 0; k < F; ++k) {
        float xv = xr[k];
        ai = fmaf(xv, w0[k], ai); af = fmaf(xv, w1[k], af);
        ag = fmaf(xv, w2[k], ag); ao = fmaf(xv, w3[k], ao);
      }
      mac512(xcat + b * LSTR,
             a.dWhh0 + (size_t)uu * H, a.dWhh0 + (size_t)(512 + uu) * H,
             a.dWhh0 + (size_t)(1024 + uu) * H, a.dWhh0 + (size_t)(1536 + uu) * H,
             ai, af, ag, ao);
      c0 = sigm(af) * c0 + sigm(ai) * tanh_f(ag);
      float h0n = sigm(ao) * tanh_f(c0);
      a.h0[(size_t)(pA ^ 1) * H * BB + (size_t)uu * BB + row] = h0n;
    }
    gbar(cnt, bar);
    // phase B: restage h0(t); h1(t-1) still in LDS cols 512+
    stage_half(xcat, a.h0 + (size_t)(pA ^ 1) * H * BB, grp, tid, 0);
    __syncthreads();
    {  // gates1
      float ai = a.db1[uu], af = a.db1[512 + uu], ag = a.db1[1024 + uu], ao = a.db1[1536 + uu];
      mac512(xcat + b * LSTR,
             a.dWih1 + (size_t)uu * H, a.dWih1 + (size_t)(512 + uu) * H,
             a.dWih1 + (size_t)(1024 + uu) * H, a.dWih1 + (size_t)(1536 + uu) * H,
             ai, af, ag, ao);
      mac512(xcat + b * LSTR + 512,
             a.dWhh1 + (size_t)uu * H, a.dWhh1 + (size_t)(512 + uu) * H,
             a.dWhh1 + (size_t)(1024 + uu) * H, a.dWhh1 + (size_t)(1536 + uu) * H,
             ai, af, ag, ao);
      c1 = sigm(af) * c1 + sigm(ai) * tanh_f(ag);
      float h1n = sigm(ao) * tanh_f(c1);
      a.h1[(size_t)pA * H * BB + (size_t)uu * BB + row] = h1n;
    }
    gbar(cnt, bar);
  }

  // epilogue: pred(95) from h1(95) (in a.h1[1])
  stage_half(xcat, a.h1 + (size_t)1 * H * BB, grp, tid, 512);
  __syncthreads();
  {
    const int bb = tid & 31, dd = (tid >> 5) & 1, ks = tid >> 6;
    const float* hr = xcat + bb * LSTR + 512 + ks * 64;
    const float* wr = a.fcW + dd * H + ks * 64;
    float s = 0.f;
    #pragma unroll 4
    for (int k = 0; k < 64; k += 4) {
      float4 hv = *(const float4*)(hr + k);
      float4 wv = *(const float4*)(wr + k);
      s = fmaf(hv.x, wv.x, s); s = fmaf(hv.y, wv.y, s);
      s = fmaf(hv.z, wv.z, s); s = fmaf(hv.w, wv.w, s);
    }
    p_part[tid] = s;
  }
  __syncthreads();
  if (w == 0 && tid < 64) {
    const int bb = tid & 31, dd = tid >> 5;
    float s = a.fcb[dd];
    #pragma unroll
    for (int ks = 0; ks < 8; ++ks) s += p_part[(ks << 6) + (dd << 5) + bb];
    a.out[(size_t)(grp * ROWS + bb) * (T_OUT * D_OUT) + (size_t)95 * D_OUT + dd] = s;
  }
}

extern "C" void kernel_launch(void* const* d_in, const int* in_sizes, int n_in,
                              void* d_out, int out_size, void* d_ws, size_t ws_size,
                              hipStream_t stream) {
  (void)in_sizes; (void)n_in; (void)out_size; (void)ws_size;
  Args a;
  a.src   = (const float*)d_in[0];
  a.eWih0 = (const float*)d_in[1];
  a.eWhh0 = (const float*)d_in[2];
  a.eb0   = (const float*)d_in[3];
  a.eWih1 = (const float*)d_in[4];
  a.eWhh1 = (const float*)d_in[5];
  a.eb1   = (const float*)d_in[6];
  a.dWih0 = (const float*)d_in[7];
  a.dWhh0 = (const float*)d_in[8];
  a.db0   = (const float*)d_in[9];
  a.dWih1 = (const float*)d_in[10];
  a.dWhh1 = (const float*)d_in[11];
  a.db1   = (const float*)d_in[12];
  a.fcW   = (const float*)d_in[13];
  a.fcb   = (const float*)d_in[14];
  a.pW    = (const float*)d_in[15];
  a.pb    = (const float*)d_in[16];
  a.out   = (float*)d_out;

  unsigned char* ws = (unsigned char*)d_ws;
  a.cnt = (unsigned*)ws;                       // 4096 bytes of counters
  float* states = (float*)(ws + 4096);
  a.h0 = states;                               // [2][H][BB]
  a.h1 = states + 2 * (size_t)H * BB;          // [2][H][BB]

  const size_t zero_bytes = 4096 + (size_t)4 * H * BB * sizeof(float);  // counters + states
  (void)hipMemsetAsync(d_ws, 0, zero_bytes, stream);

  const size_t smem_bytes = (size_t)(ROWS * LSTR + NT + 64 + ROWS * 9) * sizeof(float);  // 135040
  hipLaunchKernelGGL(forecast_kernel, dim3(NG * WPG), dim3(NT), smem_bytes, stream, a);
}

// Round 3
// 46974.857 us; speedup vs baseline: 1.2484x; 1.2484x over previous
//
#include <hip/hip_runtime.h>
#include <math.h>

#define F 8
#define H 512
#define BB 256
#define T_IN 336
#define T_OUT 96
#define D_OUT 2
#define NG 8         // batch groups
#define WPG 32       // workgroups per group (unit slices)
#define ROWS 32      // batch rows per group
#define NT 512
#define HCSTR 2064   // LDS hcat row stride BYTES (1024 bf16 *2 + 16 pad; /4 ≡ 4 mod 32)

// ws weight-plane offsets (in shorts)
#define E0H 0
#define E0L 1048576
#define E1H 2097152
#define E1L 4194304
#define D0H 6291456
#define D0L 7340032
#define D1H 8388608
#define D1L 10485760
#define W_TOTAL_SH 12582912
// h plane offsets (shorts), buf stride 131072 (= 256*512)
#define HO_H0H 0
#define HO_H0L 262144
#define HO_H1H 524288
#define HO_H1L 786432
#define HBUF 131072

using f32x4 = __attribute__((ext_vector_type(4))) float;
using s16x8 = __attribute__((ext_vector_type(8))) short;

struct Args {
  const float *src;
  const float *eWih0, *eb0, *eb1;
  const float *dWih0, *db0, *db1;
  const float *fcW, *fcb, *pW, *pb;
  const unsigned short *W;   // converted weight planes
  unsigned short *Hst;       // h state planes
  float *out;
  unsigned *cnt;
};

__device__ __forceinline__ float sigm(float x) { return 1.f / (1.f + __expf(-x)); }
__device__ __forceinline__ float tanh_f(float x) {
  float e = __expf(-2.f * fabsf(x));
  float r = (1.f - e) / (1.f + e);
  return copysignf(r, x);
}
__device__ __forceinline__ unsigned short f2bf(float x) {
  unsigned u = __float_as_uint(x);
  unsigned r = (u + 0x7FFFu + ((u >> 16) & 1u)) >> 16;
  return (unsigned short)r;
}
__device__ __forceinline__ float bf2f(unsigned short h) {
  return __uint_as_float(((unsigned)h) << 16);
}
__device__ __forceinline__ f32x4 mfma16(s16x8 a, s16x8 b, f32x4 c) {
  return __builtin_amdgcn_mfma_f32_16x16x32_bf16(a, b, c, 0, 0, 0);
}

__device__ __forceinline__ void gbar(unsigned* cnt, unsigned& bar) {
  bar += WPG;
  __threadfence();
  __syncthreads();
  if (threadIdx.x == 0) {
    __hip_atomic_fetch_add(cnt, 1u, __ATOMIC_RELAXED, __HIP_MEMORY_SCOPE_AGENT);
    long guard = 0;
    while (__hip_atomic_load(cnt, __ATOMIC_RELAXED, __HIP_MEMORY_SCOPE_AGENT) < bar) {
      __builtin_amdgcn_s_sleep(1);
      if (++guard > (1L << 22)) break;
    }
    __threadfence();
  }
  __syncthreads();
}

// 3-term split MFMA over [kb0,kb1): accA = M-tile 0 (batch 0-15), accB = M-tile 1
__device__ __forceinline__ void mfma_block(const char* HCH, const char* HCL,
    const unsigned short* WH, const unsigned short* WL, int rowShorts,
    int kb0, int kb1, int lr, int lq, int nrow, f32x4& accA, f32x4& accB) {
  const unsigned short* bh = WH + (size_t)nrow * rowShorts + lq * 8;
  const unsigned short* bl = WL + (size_t)nrow * rowShorts + lq * 8;
  const char* a0 = HCH + lr * HCSTR + lq * 16;
  const char* a1 = HCH + (16 + lr) * HCSTR + lq * 16;
  const char* l0 = HCL + lr * HCSTR + lq * 16;
  const char* l1 = HCL + (16 + lr) * HCSTR + lq * 16;
  for (int kb = kb0; kb < kb1; ++kb) {
    s16x8 vbh = *(const s16x8*)(bh + kb * 32);
    s16x8 vbl = *(const s16x8*)(bl + kb * 32);
    s16x8 ah0 = *(const s16x8*)(a0 + kb * 64);
    s16x8 ah1 = *(const s16x8*)(a1 + kb * 64);
    s16x8 al0 = *(const s16x8*)(l0 + kb * 64);
    s16x8 al1 = *(const s16x8*)(l1 + kb * 64);
    accA = mfma16(ah0, vbh, accA); accA = mfma16(al0, vbh, accA); accA = mfma16(ah0, vbl, accA);
    accB = mfma16(ah1, vbh, accB); accB = mfma16(al1, vbh, accB); accB = mfma16(ah1, vbl, accB);
  }
}

// fp32 -> bf16 hi/lo weight plane conversion
__global__ __launch_bounds__(256) void conv_kernel(
    const float* eWhh0, const float* eWih1, const float* eWhh1,
    const float* dWhh0, const float* dWih1, const float* dWhh1,
    unsigned short* W) {
  size_t i = (size_t)blockIdx.x * 256 + threadIdx.x;
  float v; size_t dh, dl;
  if (i < 1048576) { v = eWhh0[i]; dh = E0H + i; dl = E0L + i; }
  else if (i < 3145728) {
    size_t j = i - 1048576; size_t n = j >> 10, k = j & 1023;
    v = (k < 512) ? eWih1[n * 512 + k] : eWhh1[n * 512 + k - 512];
    dh = E1H + j; dl = E1L + j;
  } else if (i < 4194304) {
    size_t j = i - 3145728; v = dWhh0[j]; dh = D0H + j; dl = D0L + j;
  } else if (i < 6291456) {
    size_t j = i - 4194304; size_t n = j >> 10, k = j & 1023;
    v = (k < 512) ? dWih1[n * 512 + k] : dWhh1[n * 512 + k - 512];
    dh = D1H + j; dl = D1L + j;
  } else return;
  unsigned short hh = f2bf(v);
  unsigned short hl = f2bf(v - bf2f(hh));
  W[dh] = hh; W[dl] = hl;
}

__global__ __launch_bounds__(NT, 2) void forecast_kernel(Args a) {
  extern __shared__ char smem[];
  char* HCH = smem;                         // [32][HCSTR] hi hcat
  char* HCL = smem + 32 * HCSTR;            // lo hcat
  float* G0 = (float*)(smem + 64 * HCSTR);  // [4][32][17]
  float* G1 = G0 + 2176;
  float* p_part = G1 + 2176;                // [512]
  float* p_lds = p_part + 512;              // [64]
  float* x_lds = p_lds + 64;                // [32*9]
  float* WxL = x_lds + 288;                 // [2][4][16][8]
  float* bL = WxL + 1024;                   // [4][4][16]

  const int tid = threadIdx.x;
  const int g = blockIdx.x >> 5;      // batch group
  const int s = blockIdx.x & 31;      // unit slice (XCD-resident weights)
  const int lane = tid & 63, wid = tid >> 6;
  const int lr = lane & 15, lq = lane >> 4;
  const int gq = wid & 3, kh = wid >> 2;
  const int b = tid & 31, u = tid >> 5;     // c-update roles
  const int row_g = 32 * g + b;
  const int nrow = gq * 512 + 16 * s + lr;  // B-fragment weight row
  unsigned* cnt = a.cnt + g * 32;
  unsigned bar = 0;

  // preload x-weights + biases into LDS (per-WG constant)
  for (int e = tid; e < 1024; e += NT) {
    int set = e >> 9, rem = e & 511, q = rem >> 7, uu = (rem >> 3) & 15, k = e & 7;
    const float* sw = set ? a.dWih0 : a.eWih0;
    WxL[e] = sw[(size_t)(q * 512 + 16 * s + uu) * 8 + k];
  }
  if (tid < 256) {
    int bs = tid >> 6, q = (tid >> 4) & 3, uu = tid & 15;
    const float* sp = bs == 0 ? a.eb0 : bs == 1 ? a.eb1 : bs == 2 ? a.db0 : a.db1;
    bL[tid] = sp[q * 512 + 16 * s + uu];
  }
  __syncthreads();

  float c0 = 0.f, c1 = 0.f;
  const int r = tid >> 4, seg = tid & 15;   // staging roles

  // ================= encoder =================
  for (int t = 0; t <= T_IN; ++t) {
    const int buf = t & 1, nbuf = buf ^ 1;
    {
      const char* s00 = (const char*)(a.Hst + HO_H0H + (size_t)buf * HBUF + (size_t)(32 * g + r) * 512);
      const char* s01 = (const char*)(a.Hst + HO_H0L + (size_t)buf * HBUF + (size_t)(32 * g + r) * 512);
      const char* s10 = (const char*)(a.Hst + HO_H1H + (size_t)buf * HBUF + (size_t)(32 * g + r) * 512);
      const char* s11 = (const char*)(a.Hst + HO_H1L + (size_t)buf * HBUF + (size_t)(32 * g + r) * 512);
      char* dH = HCH + r * HCSTR; char* dL = HCL + r * HCSTR;
      #pragma unroll
      for (int j = 0; j < 4; ++j) {
        int off = seg * 16 + j * 256;
        *(float4*)(dH + off)        = *(const float4*)(s00 + off);
        *(float4*)(dH + 1024 + off) = *(const float4*)(s10 + off);
        *(float4*)(dL + off)        = *(const float4*)(s01 + off);
        *(float4*)(dL + 1024 + off) = *(const float4*)(s11 + off);
      }
    }
    __syncthreads();
    f32x4 acc00 = {0.f,0.f,0.f,0.f}, acc01 = {0.f,0.f,0.f,0.f};
    f32x4 acc10 = {0.f,0.f,0.f,0.f}, acc11 = {0.f,0.f,0.f,0.f};
    if (t < T_IN)
      mfma_block(HCH, HCL, a.W + E0H, a.W + E0L, 512, kh * 8, kh * 8 + 8, lr, lq, nrow, acc00, acc01);
    if (t >= 1)
      mfma_block(HCH, HCL, a.W + E1H, a.W + E1L, 1024, kh * 16, kh * 16 + 16, lr, lq, nrow, acc10, acc11);
    if (kh == 0) {
      #pragma unroll
      for (int j = 0; j < 4; ++j) {
        if (t < T_IN) {
          G0[gq * 544 + (lq * 4 + j) * 17 + lr] = acc00[j];
          G0[gq * 544 + (16 + lq * 4 + j) * 17 + lr] = acc01[j];
        }
        if (t >= 1) {
          G1[gq * 544 + (lq * 4 + j) * 17 + lr] = acc10[j];
          G1[gq * 544 + (16 + lq * 4 + j) * 17 + lr] = acc11[j];
        }
      }
    }
    __syncthreads();
    if (kh == 1) {
      #pragma unroll
      for (int j = 0; j < 4; ++j) {
        if (t < T_IN) {
          G0[gq * 544 + (lq * 4 + j) * 17 + lr] += acc00[j];
          G0[gq * 544 + (16 + lq * 4 + j) * 17 + lr] += acc01[j];
        }
        if (t >= 1) {
          G1[gq * 544 + (lq * 4 + j) * 17 + lr] += acc10[j];
          G1[gq * 544 + (16 + lq * 4 + j) * 17 + lr] += acc11[j];
        }
      }
    }
    __syncthreads();
    if (t < T_IN) {
      float ac[4];
      #pragma unroll
      for (int q = 0; q < 4; ++q) ac[q] = G0[q * 544 + b * 17 + u] + bL[q * 16 + u];
      const float* xr = a.src + (size_t)row_g * (T_IN * F) + t * F;
      float4 x0 = *(const float4*)xr, x1 = *(const float4*)(xr + 4);
      float xv[8] = {x0.x, x0.y, x0.z, x0.w, x1.x, x1.y, x1.z, x1.w};
      #pragma unroll
      for (int q = 0; q < 4; ++q)
        #pragma unroll
        for (int k = 0; k < 8; ++k) ac[q] = fmaf(xv[k], WxL[(q * 16 + u) * 8 + k], ac[q]);
      c0 = sigm(ac[1]) * c0 + sigm(ac[0]) * tanh_f(ac[2]);
      float h = sigm(ac[3]) * tanh_f(c0);
      unsigned short hh = f2bf(h), hl = f2bf(h - bf2f(hh));
      size_t idx = (size_t)nbuf * HBUF + (size_t)row_g * 512 + 16 * s + u;
      a.Hst[HO_H0H + idx] = hh; a.Hst[HO_H0L + idx] = hl;
    }
    if (t >= 1) {
      float ac[4];
      #pragma unroll
      for (int q = 0; q < 4; ++q) ac[q] = G1[q * 544 + b * 17 + u] + bL[64 + q * 16 + u];
      c1 = sigm(ac[1]) * c1 + sigm(ac[0]) * tanh_f(ac[2]);
      float h = sigm(ac[3]) * tanh_f(c1);
      unsigned short hh = f2bf(h), hl = f2bf(h - bf2f(hh));
      size_t idx = (size_t)nbuf * HBUF + (size_t)row_g * 512 + 16 * s + u;
      a.Hst[HO_H1H + idx] = hh; a.Hst[HO_H1L + idx] = hl;
    }
    gbar(cnt, bar);
  }

  // ================= decoder =================
  for (int t = 0; t < T_OUT; ++t) {
    const int pA = t & 1;
    // ---- phase A ----
    {
      const char* s00 = (const char*)(a.Hst + HO_H0H + (size_t)pA * HBUF + (size_t)(32 * g + r) * 512);
      const char* s01 = (const char*)(a.Hst + HO_H0L + (size_t)pA * HBUF + (size_t)(32 * g + r) * 512);
      const char* s10 = (const char*)(a.Hst + HO_H1H + (size_t)(pA ^ 1) * HBUF + (size_t)(32 * g + r) * 512);
      const char* s11 = (const char*)(a.Hst + HO_H1L + (size_t)(pA ^ 1) * HBUF + (size_t)(32 * g + r) * 512);
      char* dH = HCH + r * HCSTR; char* dL = HCL + r * HCSTR;
      #pragma unroll
      for (int j = 0; j < 4; ++j) {
        int off = seg * 16 + j * 256;
        *(float4*)(dH + off)        = *(const float4*)(s00 + off);
        *(float4*)(dH + 1024 + off) = *(const float4*)(s10 + off);
        *(float4*)(dL + off)        = *(const float4*)(s01 + off);
        *(float4*)(dL + 1024 + off) = *(const float4*)(s11 + off);
      }
    }
    __syncthreads();
    {  // fc partials from staged h1 (bf16 hi+lo)
      const int bb = tid & 31, dd = (tid >> 5) & 1, ks = tid >> 6;
      const char* hH = HCH + bb * HCSTR + 1024 + ks * 128;
      const char* hL = HCL + bb * HCSTR + 1024 + ks * 128;
      const float* wr = a.fcW + dd * 512 + ks * 64;
      float sum = 0.f;
      #pragma unroll
      for (int j = 0; j < 8; ++j) {
        s16x8 vh = *(const s16x8*)(hH + j * 16);
        s16x8 vl = *(const s16x8*)(hL + j * 16);
        #pragma unroll
        for (int e = 0; e < 8; ++e) {
          float hv = bf2f((unsigned short)vh[e]) + bf2f((unsigned short)vl[e]);
          sum = fmaf(hv, wr[j * 8 + e], sum);
        }
      }
      p_part[tid] = sum;
    }
    __syncthreads();
    if (tid < 64) {
      const int bb = tid & 31, dd = tid >> 5;
      float sum = a.fcb[dd];
      #pragma unroll
      for (int ks = 0; ks < 8; ++ks) sum += p_part[(ks << 6) + (dd << 5) + bb];
      if (t == 0) sum = a.src[(size_t)(32 * g + bb) * (T_IN * F) + 335 * F + dd * 2];
      p_lds[bb * 2 + dd] = sum;
      if (s == 0 && t > 0)
        a.out[(size_t)(32 * g + bb) * (T_OUT * D_OUT) + (size_t)(t - 1) * D_OUT + dd] = sum;
    }
    __syncthreads();
    if (tid < 256) {
      const int bb = tid & 31, j = tid >> 5;
      x_lds[bb * 9 + j] = a.pb[j] + p_lds[bb * 2] * a.pW[j * 2] + p_lds[bb * 2 + 1] * a.pW[j * 2 + 1];
    }
    __syncthreads();
    {
      f32x4 acc00 = {0.f,0.f,0.f,0.f}, acc01 = {0.f,0.f,0.f,0.f};
      mfma_block(HCH, HCL, a.W + D0H, a.W + D0L, 512, kh * 8, kh * 8 + 8, lr, lq, nrow, acc00, acc01);
      if (kh == 0) {
        #pragma unroll
        for (int j = 0; j < 4; ++j) {
          G0[gq * 544 + (lq * 4 + j) * 17 + lr] = acc00[j];
          G0[gq * 544 + (16 + lq * 4 + j) * 17 + lr] = acc01[j];
        }
      }
      __syncthreads();
      if (kh == 1) {
        #pragma unroll
        for (int j = 0; j < 4; ++j) {
          G0[gq * 544 + (lq * 4 + j) * 17 + lr] += acc00[j];
          G0[gq * 544 + (16 + lq * 4 + j) * 17 + lr] += acc01[j];
        }
      }
      __syncthreads();
      float ac[4];
      #pragma unroll
      for (int q = 0; q < 4; ++q) ac[q] = G0[q * 544 + b * 17 + u] + bL[128 + q * 16 + u];
      #pragma unroll
      for (int q = 0; q < 4; ++q)
        #pragma unroll
        for (int k = 0; k < 8; ++k) ac[q] = fmaf(x_lds[b * 9 + k], WxL[512 + (q * 16 + u) * 8 + k], ac[q]);
      c0 = sigm(ac[1]) * c0 + sigm(ac[0]) * tanh_f(ac[2]);
      float h = sigm(ac[3]) * tanh_f(c0);
      unsigned short hh = f2bf(h), hl = f2bf(h - bf2f(hh));
      size_t idx = (size_t)(pA ^ 1) * HBUF + (size_t)row_g * 512 + 16 * s + u;
      a.Hst[HO_H0H + idx] = hh; a.Hst[HO_H0L + idx] = hl;
    }
    gbar(cnt, bar);
    // ---- phase B: restage h0(t) only ----
    {
      const char* s00 = (const char*)(a.Hst + HO_H0H + (size_t)(pA ^ 1) * HBUF + (size_t)(32 * g + r) * 512);
      const char* s01 = (const char*)(a.Hst + HO_H0L + (size_t)(pA ^ 1) * HBUF + (size_t)(32 * g + r) * 512);
      char* dH = HCH + r * HCSTR; char* dL = HCL + r * HCSTR;
      #pragma unroll
      for (int j = 0; j < 4; ++j) {
        int off = seg * 16 + j * 256;
        *(float4*)(dH + off) = *(const float4*)(s00 + off);
        *(float4*)(dL + off) = *(const float4*)(s01 + off);
      }
    }
    __syncthreads();
    {
      f32x4 acc10 = {0.f,0.f,0.f,0.f}, acc11 = {0.f,0.f,0.f,0.f};
      mfma_block(HCH, HCL, a.W + D1H, a.W + D1L, 1024, kh * 16, kh * 16 + 16, lr, lq, nrow, acc10, acc11);
      if (kh == 0) {
        #pragma unroll
        for (int j = 0; j < 4; ++j) {
          G1[gq * 544 + (lq * 4 + j) * 17 + lr] = acc10[j];
          G1[gq * 544 + (16 + lq * 4 + j) * 17 + lr] = acc11[j];
        }
      }
      __syncthreads();
      if (kh == 1) {
        #pragma unroll
        for (int j = 0; j < 4; ++j) {
          G1[gq * 544 + (lq * 4 + j) * 17 + lr] += acc10[j];
          G1[gq * 544 + (16 + lq * 4 + j) * 17 + lr] += acc11[j];
        }
      }
      __syncthreads();
      float ac[4];
      #pragma unroll
      for (int q = 0; q < 4; ++q) ac[q] = G1[q * 544 + b * 17 + u] + bL[192 + q * 16 + u];
      c1 = sigm(ac[1]) * c1 + sigm(ac[0]) * tanh_f(ac[2]);
      float h = sigm(ac[3]) * tanh_f(c1);
      unsigned short hh = f2bf(h), hl = f2bf(h - bf2f(hh));
      size_t idx = (size_t)pA * HBUF + (size_t)row_g * 512 + 16 * s + u;
      a.Hst[HO_H1H + idx] = hh; a.Hst[HO_H1L + idx] = hl;
    }
    gbar(cnt, bar);
  }

  // ================= epilogue: pred(95) =================
  {
    const char* s10 = (const char*)(a.Hst + HO_H1H + (size_t)1 * HBUF + (size_t)(32 * g + r) * 512);
    const char* s11 = (const char*)(a.Hst + HO_H1L + (size_t)1 * HBUF + (size_t)(32 * g + r) * 512);
    char* dH = HCH + r * HCSTR; char* dL = HCL + r * HCSTR;
    #pragma unroll
    for (int j = 0; j < 4; ++j) {
      int off = seg * 16 + j * 256;
      *(float4*)(dH + 1024 + off) = *(const float4*)(s10 + off);
      *(float4*)(dL + 1024 + off) = *(const float4*)(s11 + off);
    }
  }
  __syncthreads();
  {
    const int bb = tid & 31, dd = (tid >> 5) & 1, ks = tid >> 6;
    const char* hH = HCH + bb * HCSTR + 1024 + ks * 128;
    const char* hL = HCL + bb * HCSTR + 1024 + ks * 128;
    const float* wr = a.fcW + dd * 512 + ks * 64;
    float sum = 0.f;
    #pragma unroll
    for (int j = 0; j < 8; ++j) {
      s16x8 vh = *(const s16x8*)(hH + j * 16);
      s16x8 vl = *(const s16x8*)(hL + j * 16);
      #pragma unroll
      for (int e = 0; e < 8; ++e) {
        float hv = bf2f((unsigned short)vh[e]) + bf2f((unsigned short)vl[e]);
        sum = fmaf(hv, wr[j * 8 + e], sum);
      }
    }
    p_part[tid] = sum;
  }
  __syncthreads();
  if (s == 0 && tid < 64) {
    const int bb = tid & 31, dd = tid >> 5;
    float sum = a.fcb[dd];
    #pragma unroll
    for (int ks = 0; ks < 8; ++ks) sum += p_part[(ks << 6) + (dd << 5) + bb];
    a.out[(size_t)(32 * g + bb) * (T_OUT * D_OUT) + (size_t)95 * D_OUT + dd] = sum;
  }
}

extern "C" void kernel_launch(void* const* d_in, const int* in_sizes, int n_in,
                              void* d_out, int out_size, void* d_ws, size_t ws_size,
                              hipStream_t stream) {
  (void)in_sizes; (void)n_in; (void)out_size; (void)ws_size;
  const float* src   = (const float*)d_in[0];
  const float* eWih0 = (const float*)d_in[1];
  const float* eWhh0 = (const float*)d_in[2];
  const float* eb0   = (const float*)d_in[3];
  const float* eWih1 = (const float*)d_in[4];
  const float* eWhh1 = (const float*)d_in[5];
  const float* eb1   = (const float*)d_in[6];
  const float* dWih0 = (const float*)d_in[7];
  const float* dWhh0 = (const float*)d_in[8];
  const float* db0   = (const float*)d_in[9];
  const float* dWih1 = (const float*)d_in[10];
  const float* dWhh1 = (const float*)d_in[11];
  const float* db1   = (const float*)d_in[12];
  const float* fcW   = (const float*)d_in[13];
  const float* fcb   = (const float*)d_in[14];
  const float* pW    = (const float*)d_in[15];
  const float* pb    = (const float*)d_in[16];

  unsigned char* ws = (unsigned char*)d_ws;
  unsigned* cnt = (unsigned*)ws;                                   // 4 KB
  unsigned short* W = (unsigned short*)(ws + 4096);                // 25.17 MB
  unsigned short* Hst = W + W_TOTAL_SH;                            // 2 MB

  (void)hipMemsetAsync(d_ws, 0, 4096, stream);
  (void)hipMemsetAsync((void*)Hst, 0, (size_t)8 * HBUF * sizeof(unsigned short), stream);

  hipLaunchKernelGGL(conv_kernel, dim3(24576), dim3(256), 0, stream,
                     eWhh0, eWih1, eWhh1, dWhh0, dWih1, dWhh1, W);

  Args a;
  a.src = src; a.eWih0 = eWih0; a.eb0 = eb0; a.eb1 = eb1;
  a.dWih0 = dWih0; a.db0 = db0; a.db1 = db1;
  a.fcW = fcW; a.fcb = fcb; a.pW = pW; a.pb = pb;
  a.W = W; a.Hst = Hst; a.out = (float*)d_out; a.cnt = cnt;

  const size_t smem_bytes = 64 * HCSTR + (2176 * 2 + 512 + 64 + 288 + 1024 + 256) * sizeof(float); // 158080
  hipLaunchKernelGGL(forecast_kernel, dim3(NG * WPG), dim3(NT), smem_bytes, stream, a);
}

// Round 4
// 11152.299 us; speedup vs baseline: 5.2586x; 4.2121x over previous
//
#include <hip/hip_runtime.h>
#include <math.h>

#define F 8
#define H 512
#define BB 256
#define T_IN 336
#define T_OUT 96
#define D_OUT 2
#define NG 8         // batch groups
#define WPG 32       // workgroups per group (unit slices)
#define ROWS 32      // batch rows per group
#define NT 512
#define HCSTR 2064   // LDS hcat row stride BYTES

// ws weight-plane offsets (in shorts)
#define E0H 0
#define E0L 1048576
#define E1H 2097152
#define E1L 4194304
#define D0H 6291456
#define D0L 7340032
#define D1H 8388608
#define D1L 10485760
#define W_TOTAL_SH 12582912
// h plane offsets (shorts), buf stride 131072 (= 256*512)
#define HO_H0H 0
#define HO_H0L 262144
#define HO_H1H 524288
#define HO_H1L 786432
#define HBUF 131072

using f32x4 = __attribute__((ext_vector_type(4))) float;
using s16x8 = __attribute__((ext_vector_type(8))) short;

struct Args {
  const float *src;
  const float *eWih0, *eb0, *eb1;
  const float *dWih0, *db0, *db1;
  const float *fcW, *fcb, *pW, *pb;
  const unsigned short *W;   // converted weight planes
  unsigned short *Hst;       // h state planes
  float *out;
  unsigned *cnt;
};

__device__ __forceinline__ float sigm(float x) { return 1.f / (1.f + __expf(-x)); }
__device__ __forceinline__ float tanh_f(float x) {
  float e = __expf(-2.f * fabsf(x));
  float r = (1.f - e) / (1.f + e);
  return copysignf(r, x);
}
__device__ __forceinline__ unsigned short f2bf(float x) {
  unsigned u = __float_as_uint(x);
  unsigned r = (u + 0x7FFFu + ((u >> 16) & 1u)) >> 16;
  return (unsigned short)r;
}
__device__ __forceinline__ float bf2f(unsigned short h) {
  return __uint_as_float(((unsigned)h) << 16);
}
__device__ __forceinline__ f32x4 mfma16(s16x8 a, s16x8 b, f32x4 c) {
  return __builtin_amdgcn_mfma_f32_16x16x32_bf16(a, b, c, 0, 0, 0);
}

// coherent (L2-bypassing) load/store: no cache-wide invalidation ever needed
__device__ __forceinline__ void ld16_cg(uint4& d, const void* p) {
  asm volatile("global_load_dwordx4 %0, %1, off sc0 sc1" : "=v"(d) : "v"(p));
}
__device__ __forceinline__ void st2_cg(void* p, unsigned v) {
  asm volatile("global_store_short %0, %1, off sc0 sc1" :: "v"(p), "v"(v) : "memory");
}

// group barrier: sc1 stores drained (vmcnt0) -> relaxed agent atomic bump/spin.
// NO acquire fence: all cross-WG reads are sc0sc1 loads (coherent per-access).
__device__ __forceinline__ void gbar(unsigned* cnt, unsigned& bar) {
  bar += WPG;
  asm volatile("s_waitcnt vmcnt(0)" ::: "memory");
  __syncthreads();
  if (threadIdx.x == 0) {
    __hip_atomic_fetch_add(cnt, 1u, __ATOMIC_RELAXED, __HIP_MEMORY_SCOPE_AGENT);
    long guard = 0;
    while (__hip_atomic_load(cnt, __ATOMIC_RELAXED, __HIP_MEMORY_SCOPE_AGENT) < bar) {
      __builtin_amdgcn_s_sleep(1);
      if (++guard > (1L << 22)) break;
    }
  }
  __syncthreads();
  asm volatile("" ::: "memory");
}

// 3-term split MFMA over [kb0,kb1)
__device__ __forceinline__ void mfma_block(const char* HCH, const char* HCL,
    const unsigned short* WH, const unsigned short* WL, int rowShorts,
    int kb0, int kb1, int lr, int lq, int nrow, f32x4& accA, f32x4& accB) {
  const unsigned short* bh = WH + (size_t)nrow * rowShorts + lq * 8;
  const unsigned short* bl = WL + (size_t)nrow * rowShorts + lq * 8;
  const char* a0 = HCH + lr * HCSTR + lq * 16;
  const char* a1 = HCH + (16 + lr) * HCSTR + lq * 16;
  const char* l0 = HCL + lr * HCSTR + lq * 16;
  const char* l1 = HCL + (16 + lr) * HCSTR + lq * 16;
  for (int kb = kb0; kb < kb1; ++kb) {
    s16x8 vbh = *(const s16x8*)(bh + kb * 32);
    s16x8 vbl = *(const s16x8*)(bl + kb * 32);
    s16x8 ah0 = *(const s16x8*)(a0 + kb * 64);
    s16x8 ah1 = *(const s16x8*)(a1 + kb * 64);
    s16x8 al0 = *(const s16x8*)(l0 + kb * 64);
    s16x8 al1 = *(const s16x8*)(l1 + kb * 64);
    accA = mfma16(ah0, vbh, accA); accA = mfma16(al0, vbh, accA); accA = mfma16(ah0, vbl, accA);
    accB = mfma16(ah1, vbh, accB); accB = mfma16(al1, vbh, accB); accB = mfma16(ah1, vbl, accB);
  }
}

__global__ __launch_bounds__(256) void conv_kernel(
    const float* eWhh0, const float* eWih1, const float* eWhh1,
    const float* dWhh0, const float* dWih1, const float* dWhh1,
    unsigned short* W) {
  size_t i = (size_t)blockIdx.x * 256 + threadIdx.x;
  float v; size_t dh, dl;
  if (i < 1048576) { v = eWhh0[i]; dh = E0H + i; dl = E0L + i; }
  else if (i < 3145728) {
    size_t j = i - 1048576; size_t n = j >> 10, k = j & 1023;
    v = (k < 512) ? eWih1[n * 512 + k] : eWhh1[n * 512 + k - 512];
    dh = E1H + j; dl = E1L + j;
  } else if (i < 4194304) {
    size_t j = i - 3145728; v = dWhh0[j]; dh = D0H + j; dl = D0L + j;
  } else if (i < 6291456) {
    size_t j = i - 4194304; size_t n = j >> 10, k = j & 1023;
    v = (k < 512) ? dWih1[n * 512 + k] : dWhh1[n * 512 + k - 512];
    dh = D1H + j; dl = D1L + j;
  } else return;
  unsigned short hh = f2bf(v);
  unsigned short hl = f2bf(v - bf2f(hh));
  W[dh] = hh; W[dl] = hl;
}

__global__ __launch_bounds__(NT, 2) void forecast_kernel(Args a) {
  extern __shared__ char smem[];
  char* HCH = smem;                         // [32][HCSTR] hi hcat
  char* HCL = smem + 32 * HCSTR;            // lo hcat
  float* G0 = (float*)(smem + 64 * HCSTR);  // [4][32][17]
  float* G1 = G0 + 2176;
  float* p_part = G1 + 2176;                // [512]
  float* p_lds = p_part + 512;              // [64]
  float* x_lds = p_lds + 64;                // [32*9]
  float* WxL = x_lds + 288;                 // [2][4][16][8]
  float* bL = WxL + 1024;                   // [4][4][16]

  const int tid = threadIdx.x;
  const int g = blockIdx.x >> 5;      // batch group
  const int s = blockIdx.x & 31;      // unit slice (s%8 = XCD -> weights L2-resident)
  const int lane = tid & 63, wid = tid >> 6;
  const int lr = lane & 15, lq = lane >> 4;
  const int gq = wid & 3, kh = wid >> 2;
  const int b = tid & 31, u = tid >> 5;
  const int row_g = 32 * g + b;
  const int nrow = gq * 512 + 16 * s + lr;
  unsigned* cnt = a.cnt + g * 32;
  unsigned bar = 0;

  for (int e = tid; e < 1024; e += NT) {
    int set = e >> 9, rem = e & 511, q = rem >> 7, uu = (rem >> 3) & 15, k = e & 7;
    const float* sw = set ? a.dWih0 : a.eWih0;
    WxL[e] = sw[(size_t)(q * 512 + 16 * s + uu) * 8 + k];
  }
  if (tid < 256) {
    int bs = tid >> 6, q = (tid >> 4) & 3, uu = tid & 15;
    const float* sp = bs == 0 ? a.eb0 : bs == 1 ? a.eb1 : bs == 2 ? a.db0 : a.db1;
    bL[tid] = sp[q * 512 + 16 * s + uu];
  }
  __syncthreads();

  float c0 = 0.f, c1 = 0.f;
  const int r = tid >> 4, seg = tid & 15;

  // ================= encoder =================
  for (int t = 0; t <= T_IN; ++t) {
    const int buf = t & 1, nbuf = buf ^ 1;
    {
      const char* s00 = (const char*)(a.Hst + HO_H0H + (size_t)buf * HBUF + (size_t)(32 * g + r) * 512) + seg * 16;
      const char* s01 = (const char*)(a.Hst + HO_H0L + (size_t)buf * HBUF + (size_t)(32 * g + r) * 512) + seg * 16;
      const char* s10 = (const char*)(a.Hst + HO_H1H + (size_t)buf * HBUF + (size_t)(32 * g + r) * 512) + seg * 16;
      const char* s11 = (const char*)(a.Hst + HO_H1L + (size_t)buf * HBUF + (size_t)(32 * g + r) * 512) + seg * 16;
      uint4 q0[4], q1[4], q2[4], q3[4];
      #pragma unroll
      for (int j = 0; j < 4; ++j) {
        ld16_cg(q0[j], s00 + j * 256);
        ld16_cg(q1[j], s01 + j * 256);
        ld16_cg(q2[j], s10 + j * 256);
        ld16_cg(q3[j], s11 + j * 256);
      }
      asm volatile("s_waitcnt vmcnt(0)" ::: "memory");
      __builtin_amdgcn_sched_barrier(0);
      char* dH = HCH + r * HCSTR + seg * 16;
      char* dL = HCL + r * HCSTR + seg * 16;
      #pragma unroll
      for (int j = 0; j < 4; ++j) {
        *(uint4*)(dH + j * 256)        = q0[j];
        *(uint4*)(dL + j * 256)        = q1[j];
        *(uint4*)(dH + 1024 + j * 256) = q2[j];
        *(uint4*)(dL + 1024 + j * 256) = q3[j];
      }
    }
    __syncthreads();
    f32x4 acc00 = {0.f,0.f,0.f,0.f}, acc01 = {0.f,0.f,0.f,0.f};
    f32x4 acc10 = {0.f,0.f,0.f,0.f}, acc11 = {0.f,0.f,0.f,0.f};
    if (t < T_IN)
      mfma_block(HCH, HCL, a.W + E0H, a.W + E0L, 512, kh * 8, kh * 8 + 8, lr, lq, nrow, acc00, acc01);
    if (t >= 1)
      mfma_block(HCH, HCL, a.W + E1H, a.W + E1L, 1024, kh * 16, kh * 16 + 16, lr, lq, nrow, acc10, acc11);
    if (kh == 0) {
      #pragma unroll
      for (int j = 0; j < 4; ++j) {
        if (t < T_IN) {
          G0[gq * 544 + (lq * 4 + j) * 17 + lr] = acc00[j];
          G0[gq * 544 + (16 + lq * 4 + j) * 17 + lr] = acc01[j];
        }
        if (t >= 1) {
          G1[gq * 544 + (lq * 4 + j) * 17 + lr] = acc10[j];
          G1[gq * 544 + (16 + lq * 4 + j) * 17 + lr] = acc11[j];
        }
      }
    }
    __syncthreads();
    if (kh == 1) {
      #pragma unroll
      for (int j = 0; j < 4; ++j) {
        if (t < T_IN) {
          G0[gq * 544 + (lq * 4 + j) * 17 + lr] += acc00[j];
          G0[gq * 544 + (16 + lq * 4 + j) * 17 + lr] += acc01[j];
        }
        if (t >= 1) {
          G1[gq * 544 + (lq * 4 + j) * 17 + lr] += acc10[j];
          G1[gq * 544 + (16 + lq * 4 + j) * 17 + lr] += acc11[j];
        }
      }
    }
    __syncthreads();
    if (t < T_IN) {
      float ac[4];
      #pragma unroll
      for (int q = 0; q < 4; ++q) ac[q] = G0[q * 544 + b * 17 + u] + bL[q * 16 + u];
      const float* xr = a.src + (size_t)row_g * (T_IN * F) + t * F;
      float4 x0 = *(const float4*)xr, x1 = *(const float4*)(xr + 4);
      float xv[8] = {x0.x, x0.y, x0.z, x0.w, x1.x, x1.y, x1.z, x1.w};
      #pragma unroll
      for (int q = 0; q < 4; ++q)
        #pragma unroll
        for (int k = 0; k < 8; ++k) ac[q] = fmaf(xv[k], WxL[(q * 16 + u) * 8 + k], ac[q]);
      c0 = sigm(ac[1]) * c0 + sigm(ac[0]) * tanh_f(ac[2]);
      float h = sigm(ac[3]) * tanh_f(c0);
      unsigned short hh = f2bf(h), hl = f2bf(h - bf2f(hh));
      size_t idx = (size_t)nbuf * HBUF + (size_t)row_g * 512 + 16 * s + u;
      st2_cg((void*)(a.Hst + HO_H0H + idx), (unsigned)hh);
      st2_cg((void*)(a.Hst + HO_H0L + idx), (unsigned)hl);
    }
    if (t >= 1) {
      float ac[4];
      #pragma unroll
      for (int q = 0; q < 4; ++q) ac[q] = G1[q * 544 + b * 17 + u] + bL[64 + q * 16 + u];
      c1 = sigm(ac[1]) * c1 + sigm(ac[0]) * tanh_f(ac[2]);
      float h = sigm(ac[3]) * tanh_f(c1);
      unsigned short hh = f2bf(h), hl = f2bf(h - bf2f(hh));
      size_t idx = (size_t)nbuf * HBUF + (size_t)row_g * 512 + 16 * s + u;
      st2_cg((void*)(a.Hst + HO_H1H + idx), (unsigned)hh);
      st2_cg((void*)(a.Hst + HO_H1L + idx), (unsigned)hl);
    }
    gbar(cnt, bar);
  }

  // ================= decoder =================
  for (int t = 0; t < T_OUT; ++t) {
    const int pA = t & 1;
    // ---- phase A ----
    {
      const char* s00 = (const char*)(a.Hst + HO_H0H + (size_t)pA * HBUF + (size_t)(32 * g + r) * 512) + seg * 16;
      const char* s01 = (const char*)(a.Hst + HO_H0L + (size_t)pA * HBUF + (size_t)(32 * g + r) * 512) + seg * 16;
      const char* s10 = (const char*)(a.Hst + HO_H1H + (size_t)(pA ^ 1) * HBUF + (size_t)(32 * g + r) * 512) + seg * 16;
      const char* s11 = (const char*)(a.Hst + HO_H1L + (size_t)(pA ^ 1) * HBUF + (size_t)(32 * g + r) * 512) + seg * 16;
      uint4 q0[4], q1[4], q2[4], q3[4];
      #pragma unroll
      for (int j = 0; j < 4; ++j) {
        ld16_cg(q0[j], s00 + j * 256);
        ld16_cg(q1[j], s01 + j * 256);
        ld16_cg(q2[j], s10 + j * 256);
        ld16_cg(q3[j], s11 + j * 256);
      }
      asm volatile("s_waitcnt vmcnt(0)" ::: "memory");
      __builtin_amdgcn_sched_barrier(0);
      char* dH = HCH + r * HCSTR + seg * 16;
      char* dL = HCL + r * HCSTR + seg * 16;
      #pragma unroll
      for (int j = 0; j < 4; ++j) {
        *(uint4*)(dH + j * 256)        = q0[j];
        *(uint4*)(dL + j * 256)        = q1[j];
        *(uint4*)(dH + 1024 + j * 256) = q2[j];
        *(uint4*)(dL + 1024 + j * 256) = q3[j];
      }
    }
    __syncthreads();
    {  // fc partials: pred(t-1) = h1(t-1) @ fcW^T + fcb
      const int bb = tid & 31, dd = (tid >> 5) & 1, ks = tid >> 6;
      const char* hH = HCH + bb * HCSTR + 1024 + ks * 128;
      const char* hL = HCL + bb * HCSTR + 1024 + ks * 128;
      const float* wr = a.fcW + dd * 512 + ks * 64;
      float sum = 0.f;
      #pragma unroll
      for (int j = 0; j < 8; ++j) {
        s16x8 vh = *(const s16x8*)(hH + j * 16);
        s16x8 vl = *(const s16x8*)(hL + j * 16);
        #pragma unroll
        for (int e = 0; e < 8; ++e) {
          float hv = bf2f((unsigned short)vh[e]) + bf2f((unsigned short)vl[e]);
          sum = fmaf(hv, wr[j * 8 + e], sum);
        }
      }
      p_part[tid] = sum;
    }
    __syncthreads();
    if (tid < 64) {
      const int bb = tid & 31, dd = tid >> 5;
      float sum = a.fcb[dd];
      #pragma unroll
      for (int ks = 0; ks < 8; ++ks) sum += p_part[(ks << 6) + (dd << 5) + bb];
      if (t == 0) sum = a.src[(size_t)(32 * g + bb) * (T_IN * F) + 335 * F + dd * 2];
      p_lds[bb * 2 + dd] = sum;
      if (s == 0 && t > 0)
        a.out[(size_t)(32 * g + bb) * (T_OUT * D_OUT) + (size_t)(t - 1) * D_OUT + dd] = sum;
    }
    __syncthreads();
    if (tid < 256) {
      const int bb = tid & 31, j = tid >> 5;
      x_lds[bb * 9 + j] = a.pb[j] + p_lds[bb * 2] * a.pW[j * 2] + p_lds[bb * 2 + 1] * a.pW[j * 2 + 1];
    }
    __syncthreads();
    {
      f32x4 acc00 = {0.f,0.f,0.f,0.f}, acc01 = {0.f,0.f,0.f,0.f};
      mfma_block(HCH, HCL, a.W + D0H, a.W + D0L, 512, kh * 8, kh * 8 + 8, lr, lq, nrow, acc00, acc01);
      if (kh == 0) {
        #pragma unroll
        for (int j = 0; j < 4; ++j) {
          G0[gq * 544 + (lq * 4 + j) * 17 + lr] = acc00[j];
          G0[gq * 544 + (16 + lq * 4 + j) * 17 + lr] = acc01[j];
        }
      }
      __syncthreads();
      if (kh == 1) {
        #pragma unroll
        for (int j = 0; j < 4; ++j) {
          G0[gq * 544 + (lq * 4 + j) * 17 + lr] += acc00[j];
          G0[gq * 544 + (16 + lq * 4 + j) * 17 + lr] += acc01[j];
        }
      }
      __syncthreads();
      float ac[4];
      #pragma unroll
      for (int q = 0; q < 4; ++q) ac[q] = G0[q * 544 + b * 17 + u] + bL[128 + q * 16 + u];
      #pragma unroll
      for (int q = 0; q < 4; ++q)
        #pragma unroll
        for (int k = 0; k < 8; ++k) ac[q] = fmaf(x_lds[b * 9 + k], WxL[512 + (q * 16 + u) * 8 + k], ac[q]);
      c0 = sigm(ac[1]) * c0 + sigm(ac[0]) * tanh_f(ac[2]);
      float h = sigm(ac[3]) * tanh_f(c0);
      unsigned short hh = f2bf(h), hl = f2bf(h - bf2f(hh));
      size_t idx = (size_t)(pA ^ 1) * HBUF + (size_t)row_g * 512 + 16 * s + u;
      st2_cg((void*)(a.Hst + HO_H0H + idx), (unsigned)hh);
      st2_cg((void*)(a.Hst + HO_H0L + idx), (unsigned)hl);
    }
    gbar(cnt, bar);
    // ---- phase B: restage h0(t) only ----
    {
      const char* s00 = (const char*)(a.Hst + HO_H0H + (size_t)(pA ^ 1) * HBUF + (size_t)(32 * g + r) * 512) + seg * 16;
      const char* s01 = (const char*)(a.Hst + HO_H0L + (size_t)(pA ^ 1) * HBUF + (size_t)(32 * g + r) * 512) + seg * 16;
      uint4 q0[4], q1[4];
      #pragma unroll
      for (int j = 0; j < 4; ++j) {
        ld16_cg(q0[j], s00 + j * 256);
        ld16_cg(q1[j], s01 + j * 256);
      }
      asm volatile("s_waitcnt vmcnt(0)" ::: "memory");
      __builtin_amdgcn_sched_barrier(0);
      char* dH = HCH + r * HCSTR + seg * 16;
      char* dL = HCL + r * HCSTR + seg * 16;
      #pragma unroll
      for (int j = 0; j < 4; ++j) {
        *(uint4*)(dH + j * 256) = q0[j];
        *(uint4*)(dL + j * 256) = q1[j];
      }
    }
    __syncthreads();
    {
      f32x4 acc10 = {0.f,0.f,0.f,0.f}, acc11 = {0.f,0.f,0.f,0.f};
      mfma_block(HCH, HCL, a.W + D1H, a.W + D1L, 1024, kh * 16, kh * 16 + 16, lr, lq, nrow, acc10, acc11);
      if (kh == 0) {
        #pragma unroll
        for (int j = 0; j < 4; ++j) {
          G1[gq * 544 + (lq * 4 + j) * 17 + lr] = acc10[j];
          G1[gq * 544 + (16 + lq * 4 + j) * 17 + lr] = acc11[j];
        }
      }
      __syncthreads();
      if (kh == 1) {
        #pragma unroll
        for (int j = 0; j < 4; ++j) {
          G1[gq * 544 + (lq * 4 + j) * 17 + lr] += acc10[j];
          G1[gq * 544 + (16 + lq * 4 + j) * 17 + lr] += acc11[j];
        }
      }
      __syncthreads();
      float ac[4];
      #pragma unroll
      for (int q = 0; q < 4; ++q) ac[q] = G1[q * 544 + b * 17 + u] + bL[192 + q * 16 + u];
      c1 = sigm(ac[1]) * c1 + sigm(ac[0]) * tanh_f(ac[2]);
      float h = sigm(ac[3]) * tanh_f(c1);
      unsigned short hh = f2bf(h), hl = f2bf(h - bf2f(hh));
      size_t idx = (size_t)pA * HBUF + (size_t)row_g * 512 + 16 * s + u;
      st2_cg((void*)(a.Hst + HO_H1H + idx), (unsigned)hh);
      st2_cg((void*)(a.Hst + HO_H1L + idx), (unsigned)hl);
    }
    gbar(cnt, bar);
  }

  // ================= epilogue: pred(95) =================
  {
    const char* s10 = (const char*)(a.Hst + HO_H1H + (size_t)1 * HBUF + (size_t)(32 * g + r) * 512) + seg * 16;
    const char* s11 = (const char*)(a.Hst + HO_H1L + (size_t)1 * HBUF + (size_t)(32 * g + r) * 512) + seg * 16;
    uint4 q0[4], q1[4];
    #pragma unroll
    for (int j = 0; j < 4; ++j) {
      ld16_cg(q0[j], s10 + j * 256);
      ld16_cg(q1[j], s11 + j * 256);
    }
    asm volatile("s_waitcnt vmcnt(0)" ::: "memory");
    __builtin_amdgcn_sched_barrier(0);
    char* dH = HCH + r * HCSTR + seg * 16;
    char* dL = HCL + r * HCSTR + seg * 16;
    #pragma unroll
    for (int j = 0; j < 4; ++j) {
      *(uint4*)(dH + 1024 + j * 256) = q0[j];
      *(uint4*)(dL + 1024 + j * 256) = q1[j];
    }
  }
  __syncthreads();
  {
    const int bb = tid & 31, dd = (tid >> 5) & 1, ks = tid >> 6;
    const char* hH = HCH + bb * HCSTR + 1024 + ks * 128;
    const char* hL = HCL + bb * HCSTR + 1024 + ks * 128;
    const float* wr = a.fcW + dd * 512 + ks * 64;
    float sum = 0.f;
    #pragma unroll
    for (int j = 0; j < 8; ++j) {
      s16x8 vh = *(const s16x8*)(hH + j * 16);
      s16x8 vl = *(const s16x8*)(hL + j * 16);
      #pragma unroll
      for (int e = 0; e < 8; ++e) {
        float hv = bf2f((unsigned short)vh[e]) + bf2f((unsigned short)vl[e]);
        sum = fmaf(hv, wr[j * 8 + e], sum);
      }
    }
    p_part[tid] = sum;
  }
  __syncthreads();
  if (s == 0 && tid < 64) {
    const int bb = tid & 31, dd = tid >> 5;
    float sum = a.fcb[dd];
    #pragma unroll
    for (int ks = 0; ks < 8; ++ks) sum += p_part[(ks << 6) + (dd << 5) + bb];
    a.out[(size_t)(32 * g + bb) * (T_OUT * D_OUT) + (size_t)95 * D_OUT + dd] = sum;
  }
}

extern "C" void kernel_launch(void* const* d_in, const int* in_sizes, int n_in,
                              void* d_out, int out_size, void* d_ws, size_t ws_size,
                              hipStream_t stream) {
  (void)in_sizes; (void)n_in; (void)out_size; (void)ws_size;
  const float* src   = (const float*)d_in[0];
  const float* eWih0 = (const float*)d_in[1];
  const float* eWhh0 = (const float*)d_in[2];
  const float* eb0   = (const float*)d_in[3];
  const float* eWih1 = (const float*)d_in[4];
  const float* eWhh1 = (const float*)d_in[5];
  const float* eb1   = (const float*)d_in[6];
  const float* dWih0 = (const float*)d_in[7];
  const float* dWhh0 = (const float*)d_in[8];
  const float* db0   = (const float*)d_in[9];
  const float* dWih1 = (const float*)d_in[10];
  const float* dWhh1 = (const float*)d_in[11];
  const float* db1   = (const float*)d_in[12];
  const float* fcW   = (const float*)d_in[13];
  const float* fcb   = (const float*)d_in[14];
  const float* pW    = (const float*)d_in[15];
  const float* pb    = (const float*)d_in[16];

  unsigned char* ws = (unsigned char*)d_ws;
  unsigned* cnt = (unsigned*)ws;                                   // 4 KB
  unsigned short* W = (unsigned short*)(ws + 4096);                // 25.17 MB
  unsigned short* Hst = W + W_TOTAL_SH;                            // 2 MB

  (void)hipMemsetAsync(d_ws, 0, 4096, stream);
  (void)hipMemsetAsync((void*)Hst, 0, (size_t)8 * HBUF * sizeof(unsigned short), stream);

  hipLaunchKernelGGL(conv_kernel, dim3(24576), dim3(256), 0, stream,
                     eWhh0, eWih1, eWhh1, dWhh0, dWih1, dWhh1, W);

  Args a;
  a.src = src; a.eWih0 = eWih0; a.eb0 = eb0; a.eb1 = eb1;
  a.dWih0 = dWih0; a.db0 = db0; a.db1 = db1;
  a.fcW = fcW; a.fcb = fcb; a.pW = pW; a.pb = pb;
  a.W = W; a.Hst = Hst; a.out = (float*)d_out; a.cnt = cnt;

  const size_t smem_bytes = 64 * HCSTR + (2176 * 2 + 512 + 64 + 288 + 1024 + 256) * sizeof(float); // 158080
  hipLaunchKernelGGL(forecast_kernel, dim3(NG * WPG), dim3(NT), smem_bytes, stream, a);
}

// Round 5
// 8260.542 us; speedup vs baseline: 7.0995x; 1.3501x over previous
//
#include <hip/hip_runtime.h>
#include <hip/hip_fp16.h>
#include <math.h>

#define F 8
#define H 512
#define T_IN 336
#define T_OUT 96
#define D_OUT 2
#define NGRP 16      // batch groups (16 rows each)
#define WPG 32       // workgroups per group (unit slices)
#define ROWS 16      // batch rows per group
#define NT 512
#define HROW 2048    // LDS hcat row stride bytes (1024 fp16)

// W offsets (shorts, fp16 planes)
#define WE0 0
#define WE1 1048576
#define WD0 3145728
#define WD1 4194304
#define W_TOTAL 6291456
// H state planes (shorts): H0 [2][256][512], H1 [2][256][512]
#define HO0 0
#define HO1 262144
#define HBUF 131072

using f32x4 = __attribute__((ext_vector_type(4))) float;
using f16x8 = __attribute__((ext_vector_type(8))) _Float16;

struct Args {
  const float *src;
  const float *eWih0, *eb0, *eb1;
  const float *dWih0, *db0, *db1;
  const float *fcW, *fcb, *pW, *pb;
  const unsigned short *W;   // fp16 weight planes
  unsigned short *Hst;       // fp16 h-state planes
  float *out;
  unsigned *cnt;
};

__device__ __forceinline__ float sigm(float x) { return 1.f / (1.f + __expf(-x)); }
__device__ __forceinline__ float tanh_f(float x) {
  float e = __expf(-2.f * fabsf(x));
  float r = (1.f - e) / (1.f + e);
  return copysignf(r, x);
}
__device__ __forceinline__ f32x4 mfma16(f16x8 a, f16x8 b, f32x4 c) {
  return __builtin_amdgcn_mfma_f32_16x16x32_f16(a, b, c, 0, 0, 0);
}

// device-coherent per-access ops: never need cache-wide maintenance
__device__ __forceinline__ void ld16_cg(uint4& d, const void* p) {
  asm volatile("global_load_dwordx4 %0, %1, off sc0 sc1" : "=v"(d) : "v"(p));
}
__device__ __forceinline__ void st2_cg(void* p, unsigned v) {
  asm volatile("global_store_short %0, %1, off sc0 sc1" :: "v"(p), "v"(v) : "memory");
}

__device__ __forceinline__ void gbar(unsigned* cnt, unsigned& bar) {
  bar += WPG;
  asm volatile("s_waitcnt vmcnt(0)" ::: "memory");   // drain sc stores
  __syncthreads();
  if (threadIdx.x == 0) {
    __hip_atomic_fetch_add(cnt, 1u, __ATOMIC_RELAXED, __HIP_MEMORY_SCOPE_AGENT);
    long guard = 0;
    while (__hip_atomic_load(cnt, __ATOMIC_RELAXED, __HIP_MEMORY_SCOPE_AGENT) < bar) {
      __builtin_amdgcn_s_sleep(1);
      if (++guard > (1L << 22)) break;
    }
  }
  __syncthreads();
  asm volatile("" ::: "memory");
}

// fp32 -> fp16 weight conversion (E0, E1=[Wih1|Whh1], D0, D1)
__global__ __launch_bounds__(256) void conv_kernel(
    const float* eWhh0, const float* eWih1, const float* eWhh1,
    const float* dWhh0, const float* dWih1, const float* dWhh1,
    unsigned short* W) {
  size_t i = (size_t)blockIdx.x * 256 + threadIdx.x;
  float v;
  if (i < 1048576) v = eWhh0[i];
  else if (i < 3145728) {
    size_t j = i - 1048576, n = j >> 10, k = j & 1023;
    v = (k < 512) ? eWih1[n * 512 + k] : eWhh1[n * 512 + k - 512];
  } else if (i < 4194304) {
    v = dWhh0[i - 3145728];
  } else if (i < W_TOTAL) {
    size_t j = i - 4194304, n = j >> 10, k = j & 1023;
    v = (k < 512) ? dWih1[n * 512 + k] : dWhh1[n * 512 + k - 512];
  } else return;
  W[i] = __half_as_ushort(__float2half_rn(v));
}

__global__ __launch_bounds__(NT, 4) void forecast_kernel(Args a) {
  extern __shared__ char smem[];
  char* HC = smem;                          // [16][2048B] fp16 hcat (h0|h1)
  float* G0 = (float*)(smem + ROWS * HROW); // [4][16][17]
  float* G1 = G0 + 1088;
  float* p_part = G1 + 1088;                // [512]
  float* p_lds = p_part + 512;              // [32]
  float* x_lds = p_lds + 32;                // [16*9]
  float* WxL = x_lds + 144;                 // [2][4][16][8] fp32 x-weights
  float* bL = WxL + 1024;                   // [4][4][16] biases

  const int tid = threadIdx.x;
  const int g = blockIdx.x >> 5;        // batch group 0..15
  const int s = blockIdx.x & 31;        // unit slice (s%8 = XCD -> L2-resident weights)
  const int lane = tid & 63, wid = tid >> 6;
  const int lr = lane & 15, lq = lane >> 4;
  const int gq = wid & 3, kh = wid >> 2;
  const int nrow = gq * 512 + 16 * s + lr;  // weight row for B-fragment
  unsigned* cnt = a.cnt + g * 32;
  unsigned bar = 0;

  // x-weights + biases to LDS
  for (int e = tid; e < 1024; e += NT) {
    int set = e >> 9, rem = e & 511, q = rem >> 7, uu = (rem >> 3) & 15, k = e & 7;
    const float* sw = set ? a.dWih0 : a.eWih0;
    WxL[e] = sw[(size_t)(q * 512 + 16 * s + uu) * 8 + k];
  }
  if (tid < 256) {
    int bs = tid >> 6, q = (tid >> 4) & 3, uu = tid & 15;
    const float* sp = bs == 0 ? a.eb0 : bs == 1 ? a.eb1 : bs == 2 ? a.db0 : a.db1;
    bL[tid] = sp[q * 512 + 16 * s + uu];
  }
  __syncthreads();

  float c0 = 0.f, c1 = 0.f;
  const int srow = tid >> 5, seg = tid & 31;   // staging roles
  const int ub = tid >> 4, uu_ = tid & 15;     // c-update roles (tid<256)

  // ================= encoder =================
  for (int t = 0; t <= T_IN; ++t) {
    const int buf = t & 1, nbuf = buf ^ 1;
    {  // stage h0(prev) -> bytes [0,1024), h1(prev) -> [1024,2048)
      const unsigned short* p0 = a.Hst + HO0 + (size_t)buf * HBUF + (size_t)(ROWS * g + srow) * 512 + seg * 8;
      const unsigned short* p1 = a.Hst + HO1 + (size_t)buf * HBUF + (size_t)(ROWS * g + srow) * 512 + seg * 8;
      uint4 q0, q1, q2, q3;
      ld16_cg(q0, p0); ld16_cg(q1, p0 + 256); ld16_cg(q2, p1); ld16_cg(q3, p1 + 256);
      asm volatile("s_waitcnt vmcnt(0)" ::: "memory");
      __builtin_amdgcn_sched_barrier(0);
      char* d = HC + srow * HROW + seg * 16;
      *(uint4*)d = q0; *(uint4*)(d + 512) = q1;
      *(uint4*)(d + 1024) = q2; *(uint4*)(d + 1536) = q3;
    }
    __syncthreads();
    f32x4 acc0 = {0.f,0.f,0.f,0.f}, acc1 = {0.f,0.f,0.f,0.f};
    const char* arow = HC + lr * HROW + lq * 16;
    if (t < T_IN) {  // layer0: K=512
      const unsigned short* wb = a.W + WE0 + (size_t)nrow * 512 + lq * 8;
      for (int kb = kh * 8; kb < kh * 8 + 8; ++kb)
        acc0 = mfma16(*(const f16x8*)(arow + kb * 64), *(const f16x8*)(wb + kb * 32), acc0);
    }
    if (t >= 1) {   // layer1: K=1024
      const unsigned short* wb = a.W + WE1 + (size_t)nrow * 1024 + lq * 8;
      for (int kb = kh * 16; kb < kh * 16 + 16; ++kb)
        acc1 = mfma16(*(const f16x8*)(arow + kb * 64), *(const f16x8*)(wb + kb * 32), acc1);
    }
    if (kh == 0) {
      #pragma unroll
      for (int j = 0; j < 4; ++j) {
        if (t < T_IN) G0[gq * 272 + (lq * 4 + j) * 17 + lr] = acc0[j];
        if (t >= 1)   G1[gq * 272 + (lq * 4 + j) * 17 + lr] = acc1[j];
      }
    }
    __syncthreads();
    if (kh == 1) {
      #pragma unroll
      for (int j = 0; j < 4; ++j) {
        if (t < T_IN) G0[gq * 272 + (lq * 4 + j) * 17 + lr] += acc0[j];
        if (t >= 1)   G1[gq * 272 + (lq * 4 + j) * 17 + lr] += acc1[j];
      }
    }
    __syncthreads();
    if (tid < 256) {
      const int b = ub, u = uu_;
      const int row_g = ROWS * g + b;
      size_t idx = (size_t)nbuf * HBUF + (size_t)row_g * 512 + 16 * s + u;
      if (t < T_IN) {
        float ac[4];
        #pragma unroll
        for (int q = 0; q < 4; ++q) ac[q] = G0[q * 272 + b * 17 + u] + bL[q * 16 + u];
        const float* xr = a.src + (size_t)row_g * (T_IN * F) + t * F;
        float4 x0 = *(const float4*)xr, x1 = *(const float4*)(xr + 4);
        float xv[8] = {x0.x, x0.y, x0.z, x0.w, x1.x, x1.y, x1.z, x1.w};
        #pragma unroll
        for (int q = 0; q < 4; ++q)
          #pragma unroll
          for (int k = 0; k < 8; ++k) ac[q] = fmaf(xv[k], WxL[(q * 16 + u) * 8 + k], ac[q]);
        c0 = sigm(ac[1]) * c0 + sigm(ac[0]) * tanh_f(ac[2]);
        float h = sigm(ac[3]) * tanh_f(c0);
        st2_cg((void*)(a.Hst + HO0 + idx), (unsigned)__half_as_ushort(__float2half_rn(h)));
      }
      if (t >= 1) {
        float ac[4];
        #pragma unroll
        for (int q = 0; q < 4; ++q) ac[q] = G1[q * 272 + b * 17 + u] + bL[64 + q * 16 + u];
        c1 = sigm(ac[1]) * c1 + sigm(ac[0]) * tanh_f(ac[2]);
        float h = sigm(ac[3]) * tanh_f(c1);
        st2_cg((void*)(a.Hst + HO1 + idx), (unsigned)__half_as_ushort(__float2half_rn(h)));
      }
    }
    gbar(cnt, bar);
  }

  // ================= decoder =================
  for (int t = 0; t < T_OUT; ++t) {
    const int pA = t & 1;
    {  // stage h0(t-1), h1(t-1)
      const unsigned short* p0 = a.Hst + HO0 + (size_t)pA * HBUF + (size_t)(ROWS * g + srow) * 512 + seg * 8;
      const unsigned short* p1 = a.Hst + HO1 + (size_t)(pA ^ 1) * HBUF + (size_t)(ROWS * g + srow) * 512 + seg * 8;
      uint4 q0, q1, q2, q3;
      ld16_cg(q0, p0); ld16_cg(q1, p0 + 256); ld16_cg(q2, p1); ld16_cg(q3, p1 + 256);
      asm volatile("s_waitcnt vmcnt(0)" ::: "memory");
      __builtin_amdgcn_sched_barrier(0);
      char* d = HC + srow * HROW + seg * 16;
      *(uint4*)d = q0; *(uint4*)(d + 512) = q1;
      *(uint4*)(d + 1024) = q2; *(uint4*)(d + 1536) = q3;
    }
    __syncthreads();
    {  // fc partials: pred(t-1) = h1(t-1) @ fcW^T
      const int bb = tid & 15, dd = (tid >> 4) & 1, ks = tid >> 5;
      const char* hp = HC + bb * HROW + 1024 + ks * 64;
      const float* wr = a.fcW + dd * 512 + ks * 32;
      float sum = 0.f;
      #pragma unroll
      for (int j = 0; j < 4; ++j) {
        f16x8 v = *(const f16x8*)(hp + j * 16);
        #pragma unroll
        for (int e = 0; e < 8; ++e) sum = fmaf((float)v[e], wr[j * 8 + e], sum);
      }
      p_part[tid] = sum;
    }
    __syncthreads();
    if (tid < 32) {
      const int bb = tid & 15, dd = tid >> 4;
      float sum = a.fcb[dd];
      #pragma unroll
      for (int ks = 0; ks < 16; ++ks) sum += p_part[ks * 32 + dd * 16 + bb];
      if (t == 0) sum = a.src[(size_t)(ROWS * g + bb) * (T_IN * F) + 335 * F + dd * 2];
      p_lds[bb * 2 + dd] = sum;
      if (s == 0 && t > 0)
        a.out[(size_t)(ROWS * g + bb) * (T_OUT * D_OUT) + (size_t)(t - 1) * D_OUT + dd] = sum;
    }
    __syncthreads();
    if (tid < 128) {  // x = pred @ pW^T + pb
      const int bb = tid & 15, j = tid >> 4;
      x_lds[bb * 9 + j] = a.pb[j] + p_lds[bb * 2] * a.pW[j * 2] + p_lds[bb * 2 + 1] * a.pW[j * 2 + 1];
    }
    __syncthreads();
    {  // layer0 decoder
      f32x4 acc0 = {0.f,0.f,0.f,0.f};
      const char* arow = HC + lr * HROW + lq * 16;
      const unsigned short* wb = a.W + WD0 + (size_t)nrow * 512 + lq * 8;
      for (int kb = kh * 8; kb < kh * 8 + 8; ++kb)
        acc0 = mfma16(*(const f16x8*)(arow + kb * 64), *(const f16x8*)(wb + kb * 32), acc0);
      if (kh == 0) {
        #pragma unroll
        for (int j = 0; j < 4; ++j) G0[gq * 272 + (lq * 4 + j) * 17 + lr] = acc0[j];
      }
      __syncthreads();
      if (kh == 1) {
        #pragma unroll
        for (int j = 0; j < 4; ++j) G0[gq * 272 + (lq * 4 + j) * 17 + lr] += acc0[j];
      }
      __syncthreads();
      if (tid < 256) {
        const int b = ub, u = uu_;
        const int row_g = ROWS * g + b;
        float ac[4];
        #pragma unroll
        for (int q = 0; q < 4; ++q) ac[q] = G0[q * 272 + b * 17 + u] + bL[128 + q * 16 + u];
        #pragma unroll
        for (int q = 0; q < 4; ++q)
          #pragma unroll
          for (int k = 0; k < 8; ++k) ac[q] = fmaf(x_lds[b * 9 + k], WxL[512 + (q * 16 + u) * 8 + k], ac[q]);
        c0 = sigm(ac[1]) * c0 + sigm(ac[0]) * tanh_f(ac[2]);
        float h = sigm(ac[3]) * tanh_f(c0);
        size_t idx = (size_t)(pA ^ 1) * HBUF + (size_t)row_g * 512 + 16 * s + u;
        st2_cg((void*)(a.Hst + HO0 + idx), (unsigned)__half_as_ushort(__float2half_rn(h)));
      }
    }
    gbar(cnt, bar);
    {  // stage h0(t) only
      const unsigned short* p0 = a.Hst + HO0 + (size_t)(pA ^ 1) * HBUF + (size_t)(ROWS * g + srow) * 512 + seg * 8;
      uint4 q0, q1;
      ld16_cg(q0, p0); ld16_cg(q1, p0 + 256);
      asm volatile("s_waitcnt vmcnt(0)" ::: "memory");
      __builtin_amdgcn_sched_barrier(0);
      char* d = HC + srow * HROW + seg * 16;
      *(uint4*)d = q0; *(uint4*)(d + 512) = q1;
    }
    __syncthreads();
    {  // layer1 decoder
      f32x4 acc1 = {0.f,0.f,0.f,0.f};
      const char* arow = HC + lr * HROW + lq * 16;
      const unsigned short* wb = a.W + WD1 + (size_t)nrow * 1024 + lq * 8;
      for (int kb = kh * 16; kb < kh * 16 + 16; ++kb)
        acc1 = mfma16(*(const f16x8*)(arow + kb * 64), *(const f16x8*)(wb + kb * 32), acc1);
      if (kh == 0) {
        #pragma unroll
        for (int j = 0; j < 4; ++j) G1[gq * 272 + (lq * 4 + j) * 17 + lr] = acc1[j];
      }
      __syncthreads();
      if (kh == 1) {
        #pragma unroll
        for (int j = 0; j < 4; ++j) G1[gq * 272 + (lq * 4 + j) * 17 + lr] += acc1[j];
      }
      __syncthreads();
      if (tid < 256) {
        const int b = ub, u = uu_;
        const int row_g = ROWS * g + b;
        float ac[4];
        #pragma unroll
        for (int q = 0; q < 4; ++q) ac[q] = G1[q * 272 + b * 17 + u] + bL[192 + q * 16 + u];
        c1 = sigm(ac[1]) * c1 + sigm(ac[0]) * tanh_f(ac[2]);
        float h = sigm(ac[3]) * tanh_f(c1);
        size_t idx = (size_t)pA * HBUF + (size_t)row_g * 512 + 16 * s + u;
        st2_cg((void*)(a.Hst + HO1 + idx), (unsigned)__half_as_ushort(__float2half_rn(h)));
      }
    }
    gbar(cnt, bar);
  }

  // ================= epilogue: pred(95) from h1(95) in buf 1 =================
  {
    const unsigned short* p1 = a.Hst + HO1 + (size_t)1 * HBUF + (size_t)(ROWS * g + srow) * 512 + seg * 8;
    uint4 q0, q1;
    ld16_cg(q0, p1); ld16_cg(q1, p1 + 256);
    asm volatile("s_waitcnt vmcnt(0)" ::: "memory");
    __builtin_amdgcn_sched_barrier(0);
    char* d = HC + srow * HROW + seg * 16;
    *(uint4*)(d + 1024) = q0; *(uint4*)(d + 1536) = q1;
  }
  __syncthreads();
  {
    const int bb = tid & 15, dd = (tid >> 4) & 1, ks = tid >> 5;
    const char* hp = HC + bb * HROW + 1024 + ks * 64;
    const float* wr = a.fcW + dd * 512 + ks * 32;
    float sum = 0.f;
    #pragma unroll
    for (int j = 0; j < 4; ++j) {
      f16x8 v = *(const f16x8*)(hp + j * 16);
      #pragma unroll
      for (int e = 0; e < 8; ++e) sum = fmaf((float)v[e], wr[j * 8 + e], sum);
    }
    p_part[tid] = sum;
  }
  __syncthreads();
  if (s == 0 && tid < 32) {
    const int bb = tid & 15, dd = tid >> 4;
    float sum = a.fcb[dd];
    #pragma unroll
    for (int ks = 0; ks < 16; ++ks) sum += p_part[ks * 32 + dd * 16 + bb];
    a.out[(size_t)(ROWS * g + bb) * (T_OUT * D_OUT) + (size_t)95 * D_OUT + dd] = sum;
  }
}

extern "C" void kernel_launch(void* const* d_in, const int* in_sizes, int n_in,
                              void* d_out, int out_size, void* d_ws, size_t ws_size,
                              hipStream_t stream) {
  (void)in_sizes; (void)n_in; (void)out_size; (void)ws_size;
  const float* src   = (const float*)d_in[0];
  const float* eWih0 = (const float*)d_in[1];
  const float* eWhh0 = (const float*)d_in[2];
  const float* eb0   = (const float*)d_in[3];
  const float* eWih1 = (const float*)d_in[4];
  const float* eWhh1 = (const float*)d_in[5];
  const float* eb1   = (const float*)d_in[6];
  const float* dWih0 = (const float*)d_in[7];
  const float* dWhh0 = (const float*)d_in[8];
  const float* db0   = (const float*)d_in[9];
  const float* dWih1 = (const float*)d_in[10];
  const float* dWhh1 = (const float*)d_in[11];
  const float* db1   = (const float*)d_in[12];
  const float* fcW   = (const float*)d_in[13];
  const float* fcb   = (const float*)d_in[14];
  const float* pW    = (const float*)d_in[15];
  const float* pb    = (const float*)d_in[16];

  unsigned char* ws = (unsigned char*)d_ws;
  unsigned* cnt = (unsigned*)ws;                       // 4 KB
  unsigned short* W = (unsigned short*)(ws + 4096);    // 12.6 MB fp16 weights
  unsigned short* Hst = W + W_TOTAL;                   // 1 MB fp16 h-state

  (void)hipMemsetAsync(d_ws, 0, 4096, stream);
  (void)hipMemsetAsync((void*)Hst, 0, (size_t)4 * HBUF * sizeof(unsigned short), stream);

  hipLaunchKernelGGL(conv_kernel, dim3(W_TOTAL / 256), dim3(256), 0, stream,
                     eWhh0, eWih1, eWhh1, dWhh0, dWih1, dWhh1, W);

  Args a;
  a.src = src; a.eWih0 = eWih0; a.eb0 = eb0; a.eb1 = eb1;
  a.dWih0 = dWih0; a.db0 = db0; a.db1 = db1;
  a.fcW = fcW; a.fcb = fcb; a.pW = pW; a.pb = pb;
  a.W = W; a.Hst = Hst; a.out = (float*)d_out; a.cnt = cnt;

  // LDS: 32768 (HC) + (1088+1088+512+32+144+1024+256)*4 = 49344 B -> 2+ blocks/CU
  const size_t smem_bytes = (size_t)ROWS * HROW + (1088 + 1088 + 512 + 32 + 144 + 1024 + 256) * sizeof(float);
  hipLaunchKernelGGL(forecast_kernel, dim3(NGRP * WPG), dim3(NT), smem_bytes, stream, a);
}

// Round 6
// 7353.605 us; speedup vs baseline: 7.9751x; 1.1233x over previous
//
#include <hip/hip_runtime.h>
#include <hip/hip_fp16.h>
#include <math.h>

#define F 8
#define H 512
#define T_IN 336
#define T_OUT 96
#define D_OUT 2
#define NGRP 16      // batch groups (16 rows each)
#define WPG 32       // workgroups per group (unit slices)
#define ROWS 16      // batch rows per group
#define NT 512
#define HROW 2048    // LDS hcat row stride bytes (1024 fp16)

// W offsets (shorts, fp16 planes)
#define WE0 0
#define WE1 1048576
#define WD0 3145728
#define WD1 4194304
#define W_TOTAL 6291456
// H state planes (shorts)
#define HO0 0
#define HO1 262144
#define HBUF 131072

using f32x4 = __attribute__((ext_vector_type(4))) float;
using f16x8 = __attribute__((ext_vector_type(8))) _Float16;

struct Args {
  const float *src;
  const float *eWih0, *eb0, *eb1;
  const float *dWih0, *db0, *db1;
  const float *fcW, *fcb, *pW, *pb;
  const unsigned short *W;   // fp16 weight planes
  unsigned short *Hst;       // fp16 h-state planes
  float *out;
  unsigned *cnt;
};

__device__ __forceinline__ float sigm(float x) { return 1.f / (1.f + __expf(-x)); }
__device__ __forceinline__ float tanh_f(float x) {
  float e = __expf(-2.f * fabsf(x));
  float r = (1.f - e) / (1.f + e);
  return copysignf(r, x);
}
__device__ __forceinline__ f32x4 mfma16(f16x8 a, f16x8 b, f32x4 c) {
  return __builtin_amdgcn_mfma_f32_16x16x32_f16(a, b, c, 0, 0, 0);
}

// device-coherent per-access ops: never need cache-wide maintenance
__device__ __forceinline__ void ld16_cg(uint4& d, const void* p) {
  asm volatile("global_load_dwordx4 %0, %1, off sc0 sc1" : "=v"(d) : "v"(p));
}
__device__ __forceinline__ void st2_cg(void* p, unsigned v) {
  asm volatile("global_store_short %0, %1, off sc0 sc1" :: "v"(p), "v"(v) : "memory");
}

__device__ __forceinline__ void gbar(unsigned* cnt, unsigned& bar) {
  bar += WPG;
  asm volatile("s_waitcnt vmcnt(0)" ::: "memory");   // drain sc stores
  __syncthreads();
  if (threadIdx.x == 0) {
    __hip_atomic_fetch_add(cnt, 1u, __ATOMIC_RELAXED, __HIP_MEMORY_SCOPE_AGENT);
    long guard = 0;
    while (__hip_atomic_load(cnt, __ATOMIC_RELAXED, __HIP_MEMORY_SCOPE_AGENT) < bar) {
      __builtin_amdgcn_s_sleep(1);
      if (++guard > (1L << 22)) break;
    }
  }
  __syncthreads();
  asm volatile("" ::: "memory");
}

// fp32 -> fp16 weight conversion (E0, E1=[Wih1|Whh1], D0, D1)
__global__ __launch_bounds__(256) void conv_kernel(
    const float* eWhh0, const float* eWih1, const float* eWhh1,
    const float* dWhh0, const float* dWih1, const float* dWhh1,
    unsigned short* W) {
  size_t i = (size_t)blockIdx.x * 256 + threadIdx.x;
  float v;
  if (i < 1048576) v = eWhh0[i];
  else if (i < 3145728) {
    size_t j = i - 1048576, n = j >> 10, k = j & 1023;
    v = (k < 512) ? eWih1[n * 512 + k] : eWhh1[n * 512 + k - 512];
  } else if (i < 4194304) {
    v = dWhh0[i - 3145728];
  } else if (i < W_TOTAL) {
    size_t j = i - 4194304, n = j >> 10, k = j & 1023;
    v = (k < 512) ? dWih1[n * 512 + k] : dWhh1[n * 512 + k - 512];
  } else return;
  W[i] = __half_as_ushort(__float2half_rn(v));
}

__global__ __launch_bounds__(NT, 4) void forecast_kernel(Args a) {
  extern __shared__ char smem[];
  char* HC = smem;                          // [16][2048B] fp16 hcat (h0|h1), XOR-swizzled
  float* G0 = (float*)(smem + ROWS * HROW); // [2(kh)][4][16][17]
  float* G1 = G0 + 2176;                    // [2(kh)][4][16][17]
  float* p_part = G1 + 2176;                // [512]
  float* p_lds = p_part + 512;              // [32]
  float* x_lds = p_lds + 32;                // [16*9]
  float* WxL = x_lds + 144;                 // [2][4][16][8] fp32 x-weights
  float* bL = WxL + 1024;                   // [4][4][16] biases

  const int tid = threadIdx.x;
  const int g = blockIdx.x >> 5;        // batch group 0..15
  const int s = blockIdx.x & 31;        // unit slice (s%8 = XCD -> L2-resident weights)
  const int lane = tid & 63, wid = tid >> 6;
  const int lr = lane & 15, lq = lane >> 4;
  const int gq = wid & 3, kh = wid >> 2;
  const int nrow = gq * 512 + 16 * s + lr;  // weight row for B-fragment
  unsigned* cnt = a.cnt + g * 32;
  unsigned bar = 0;

  // x-weights + biases to LDS
  for (int e = tid; e < 1024; e += NT) {
    int set = e >> 9, rem = e & 511, q = rem >> 7, uu = (rem >> 3) & 15, k = e & 7;
    const float* sw = set ? a.dWih0 : a.eWih0;
    WxL[e] = sw[(size_t)(q * 512 + 16 * s + uu) * 8 + k];
  }
  if (tid < 256) {
    int bs = tid >> 6, q = (tid >> 4) & 3, uu = tid & 15;
    const float* sp = bs == 0 ? a.eb0 : bs == 1 ? a.eb1 : bs == 2 ? a.db0 : a.db1;
    bL[tid] = sp[q * 512 + 16 * s + uu];
  }
  __syncthreads();

  float c0 = 0.f, c1 = 0.f;
  const int srow = tid >> 5, seg = tid & 31;   // staging roles
  const int ub = tid >> 4, uu_ = tid & 15;     // c-update roles (tid<256)
  const int wswz = (srow & 7) << 4;            // staging write swizzle
  const int aswz = (lr & 7) << 4;              // MFMA A-read swizzle

  // ================= encoder =================
  for (int t = 0; t <= T_IN; ++t) {
    const int buf = t & 1, nbuf = buf ^ 1;
    {  // stage h0(prev) -> [0,1024), h1(prev) -> [1024,2048), swizzled
      const unsigned short* p0 = a.Hst + HO0 + (size_t)buf * HBUF + (size_t)(ROWS * g + srow) * 512 + seg * 8;
      const unsigned short* p1 = a.Hst + HO1 + (size_t)buf * HBUF + (size_t)(ROWS * g + srow) * 512 + seg * 8;
      uint4 q0, q1, q2, q3;
      ld16_cg(q0, p0); ld16_cg(q1, p0 + 256); ld16_cg(q2, p1); ld16_cg(q3, p1 + 256);
      asm volatile("s_waitcnt vmcnt(0)" ::: "memory");
      __builtin_amdgcn_sched_barrier(0);
      char* d = HC + srow * HROW + ((seg * 16) ^ wswz);
      *(uint4*)d = q0; *(uint4*)(d + 512) = q1;
      *(uint4*)(d + 1024) = q2; *(uint4*)(d + 1536) = q3;
    }
    __syncthreads();
    f32x4 acc0 = {0.f,0.f,0.f,0.f}, acc1 = {0.f,0.f,0.f,0.f};
    const char* arow = HC + lr * HROW;
    if (t < T_IN) {  // layer0: K=512
      const unsigned short* wb = a.W + WE0 + (size_t)nrow * 512 + lq * 8;
      for (int kb = kh * 8; kb < kh * 8 + 8; ++kb)
        acc0 = mfma16(*(const f16x8*)(arow + ((lq * 16 + kb * 64) ^ aswz)),
                      *(const f16x8*)(wb + kb * 32), acc0);
    }
    if (t >= 1) {   // layer1: K=1024
      const unsigned short* wb = a.W + WE1 + (size_t)nrow * 1024 + lq * 8;
      for (int kb = kh * 16; kb < kh * 16 + 16; ++kb)
        acc1 = mfma16(*(const f16x8*)(arow + ((lq * 16 + kb * 64) ^ aswz)),
                      *(const f16x8*)(wb + kb * 32), acc1);
    }
    // both kh halves write disjoint slabs; ONE sync; c-update sums in VALU
    #pragma unroll
    for (int j = 0; j < 4; ++j) {
      if (t < T_IN) G0[kh * 1088 + gq * 272 + (lq * 4 + j) * 17 + lr] = acc0[j];
      if (t >= 1)   G1[kh * 1088 + gq * 272 + (lq * 4 + j) * 17 + lr] = acc1[j];
    }
    __syncthreads();
    if (tid < 256) {
      const int b = ub, u = uu_;
      const int row_g = ROWS * g + b;
      size_t idx = (size_t)nbuf * HBUF + (size_t)row_g * 512 + 16 * s + u;
      if (t < T_IN) {
        float ac[4];
        #pragma unroll
        for (int q = 0; q < 4; ++q)
          ac[q] = G0[q * 272 + b * 17 + u] + G0[1088 + q * 272 + b * 17 + u] + bL[q * 16 + u];
        const float* xr = a.src + (size_t)row_g * (T_IN * F) + t * F;
        float4 x0 = *(const float4*)xr, x1 = *(const float4*)(xr + 4);
        float xv[8] = {x0.x, x0.y, x0.z, x0.w, x1.x, x1.y, x1.z, x1.w};
        #pragma unroll
        for (int q = 0; q < 4; ++q)
          #pragma unroll
          for (int k = 0; k < 8; ++k) ac[q] = fmaf(xv[k], WxL[(q * 16 + u) * 8 + k], ac[q]);
        c0 = sigm(ac[1]) * c0 + sigm(ac[0]) * tanh_f(ac[2]);
        float h = sigm(ac[3]) * tanh_f(c0);
        st2_cg((void*)(a.Hst + HO0 + idx), (unsigned)__half_as_ushort(__float2half_rn(h)));
      }
      if (t >= 1) {
        float ac[4];
        #pragma unroll
        for (int q = 0; q < 4; ++q)
          ac[q] = G1[q * 272 + b * 17 + u] + G1[1088 + q * 272 + b * 17 + u] + bL[64 + q * 16 + u];
        c1 = sigm(ac[1]) * c1 + sigm(ac[0]) * tanh_f(ac[2]);
        float h = sigm(ac[3]) * tanh_f(c1);
        st2_cg((void*)(a.Hst + HO1 + idx), (unsigned)__half_as_ushort(__float2half_rn(h)));
      }
    }
    gbar(cnt, bar);
  }

  // ================= decoder =================
  for (int t = 0; t < T_OUT; ++t) {
    const int pA = t & 1;
    {  // stage h0(t-1), h1(t-1)
      const unsigned short* p0 = a.Hst + HO0 + (size_t)pA * HBUF + (size_t)(ROWS * g + srow) * 512 + seg * 8;
      const unsigned short* p1 = a.Hst + HO1 + (size_t)(pA ^ 1) * HBUF + (size_t)(ROWS * g + srow) * 512 + seg * 8;
      uint4 q0, q1, q2, q3;
      ld16_cg(q0, p0); ld16_cg(q1, p0 + 256); ld16_cg(q2, p1); ld16_cg(q3, p1 + 256);
      asm volatile("s_waitcnt vmcnt(0)" ::: "memory");
      __builtin_amdgcn_sched_barrier(0);
      char* d = HC + srow * HROW + ((seg * 16) ^ wswz);
      *(uint4*)d = q0; *(uint4*)(d + 512) = q1;
      *(uint4*)(d + 1024) = q2; *(uint4*)(d + 1536) = q3;
    }
    __syncthreads();
    {  // fc partials: pred(t-1) = h1(t-1) @ fcW^T
      const int bb = tid & 15, dd = (tid >> 4) & 1, ks = tid >> 5;
      const char* hp = HC + bb * HROW + 1024;
      const int fswz = (bb & 7) << 4;
      const float* wr = a.fcW + dd * 512 + ks * 32;
      float sum = 0.f;
      #pragma unroll
      for (int j = 0; j < 4; ++j) {
        f16x8 v = *(const f16x8*)(hp + ((ks * 64 + j * 16) ^ fswz));
        #pragma unroll
        for (int e = 0; e < 8; ++e) sum = fmaf((float)v[e], wr[j * 8 + e], sum);
      }
      p_part[tid] = sum;
    }
    __syncthreads();
    if (tid < 32) {
      const int bb = tid & 15, dd = tid >> 4;
      float sum = a.fcb[dd];
      #pragma unroll
      for (int ks = 0; ks < 16; ++ks) sum += p_part[ks * 32 + dd * 16 + bb];
      if (t == 0) sum = a.src[(size_t)(ROWS * g + bb) * (T_IN * F) + 335 * F + dd * 2];
      p_lds[bb * 2 + dd] = sum;
      if (s == 0 && t > 0)
        a.out[(size_t)(ROWS * g + bb) * (T_OUT * D_OUT) + (size_t)(t - 1) * D_OUT + dd] = sum;
    }
    __syncthreads();
    if (tid < 128) {  // x = pred @ pW^T + pb
      const int bb = tid & 15, j = tid >> 4;
      x_lds[bb * 9 + j] = a.pb[j] + p_lds[bb * 2] * a.pW[j * 2] + p_lds[bb * 2 + 1] * a.pW[j * 2 + 1];
    }
    __syncthreads();
    {  // layer0 decoder
      f32x4 acc0 = {0.f,0.f,0.f,0.f};
      const char* arow = HC + lr * HROW;
      const unsigned short* wb = a.W + WD0 + (size_t)nrow * 512 + lq * 8;
      for (int kb = kh * 8; kb < kh * 8 + 8; ++kb)
        acc0 = mfma16(*(const f16x8*)(arow + ((lq * 16 + kb * 64) ^ aswz)),
                      *(const f16x8*)(wb + kb * 32), acc0);
      #pragma unroll
      for (int j = 0; j < 4; ++j)
        G0[kh * 1088 + gq * 272 + (lq * 4 + j) * 17 + lr] = acc0[j];
      __syncthreads();
      if (tid < 256) {
        const int b = ub, u = uu_;
        const int row_g = ROWS * g + b;
        float ac[4];
        #pragma unroll
        for (int q = 0; q < 4; ++q)
          ac[q] = G0[q * 272 + b * 17 + u] + G0[1088 + q * 272 + b * 17 + u] + bL[128 + q * 16 + u];
        #pragma unroll
        for (int q = 0; q < 4; ++q)
          #pragma unroll
          for (int k = 0; k < 8; ++k) ac[q] = fmaf(x_lds[b * 9 + k], WxL[512 + (q * 16 + u) * 8 + k], ac[q]);
        c0 = sigm(ac[1]) * c0 + sigm(ac[0]) * tanh_f(ac[2]);
        float h = sigm(ac[3]) * tanh_f(c0);
        size_t idx = (size_t)(pA ^ 1) * HBUF + (size_t)row_g * 512 + 16 * s + u;
        st2_cg((void*)(a.Hst + HO0 + idx), (unsigned)__half_as_ushort(__float2half_rn(h)));
      }
    }
    gbar(cnt, bar);
    {  // stage h0(t) only
      const unsigned short* p0 = a.Hst + HO0 + (size_t)(pA ^ 1) * HBUF + (size_t)(ROWS * g + srow) * 512 + seg * 8;
      uint4 q0, q1;
      ld16_cg(q0, p0); ld16_cg(q1, p0 + 256);
      asm volatile("s_waitcnt vmcnt(0)" ::: "memory");
      __builtin_amdgcn_sched_barrier(0);
      char* d = HC + srow * HROW + ((seg * 16) ^ wswz);
      *(uint4*)d = q0; *(uint4*)(d + 512) = q1;
    }
    __syncthreads();
    {  // layer1 decoder
      f32x4 acc1 = {0.f,0.f,0.f,0.f};
      const char* arow = HC + lr * HROW;
      const unsigned short* wb = a.W + WD1 + (size_t)nrow * 1024 + lq * 8;
      for (int kb = kh * 16; kb < kh * 16 + 16; ++kb)
        acc1 = mfma16(*(const f16x8*)(arow + ((lq * 16 + kb * 64) ^ aswz)),
                      *(const f16x8*)(wb + kb * 32), acc1);
      #pragma unroll
      for (int j = 0; j < 4; ++j)
        G1[kh * 1088 + gq * 272 + (lq * 4 + j) * 17 + lr] = acc1[j];
      __syncthreads();
      if (tid < 256) {
        const int b = ub, u = uu_;
        const int row_g = ROWS * g + b;
        float ac[4];
        #pragma unroll
        for (int q = 0; q < 4; ++q)
          ac[q] = G1[q * 272 + b * 17 + u] + G1[1088 + q * 272 + b * 17 + u] + bL[192 + q * 16 + u];
        c1 = sigm(ac[1]) * c1 + sigm(ac[0]) * tanh_f(ac[2]);
        float h = sigm(ac[3]) * tanh_f(c1);
        size_t idx = (size_t)pA * HBUF + (size_t)row_g * 512 + 16 * s + u;
        st2_cg((void*)(a.Hst + HO1 + idx), (unsigned)__half_as_ushort(__float2half_rn(h)));
      }
    }
    gbar(cnt, bar);
  }

  // ================= epilogue: pred(95) from h1(95) in buf 1 =================
  {
    const unsigned short* p1 = a.Hst + HO1 + (size_t)1 * HBUF + (size_t)(ROWS * g + srow) * 512 + seg * 8;
    uint4 q0, q1;
    ld16_cg(q0, p1); ld16_cg(q1, p1 + 256);
    asm volatile("s_waitcnt vmcnt(0)" ::: "memory");
    __builtin_amdgcn_sched_barrier(0);
    char* d = HC + srow * HROW + ((seg * 16) ^ wswz);
    *(uint4*)(d + 1024) = q0; *(uint4*)(d + 1536) = q1;
  }
  __syncthreads();
  {
    const int bb = tid & 15, dd = (tid >> 4) & 1, ks = tid >> 5;
    const char* hp = HC + bb * HROW + 1024;
    const int fswz = (bb & 7) << 4;
    const float* wr = a.fcW + dd * 512 + ks * 32;
    float sum = 0.f;
    #pragma unroll
    for (int j = 0; j < 4; ++j) {
      f16x8 v = *(const f16x8*)(hp + ((ks * 64 + j * 16) ^ fswz));
      #pragma unroll
      for (int e = 0; e < 8; ++e) sum = fmaf((float)v[e], wr[j * 8 + e], sum);
    }
    p_part[tid] = sum;
  }
  __syncthreads();
  if (s == 0 && tid < 32) {
    const int bb = tid & 15, dd = tid >> 4;
    float sum = a.fcb[dd];
    #pragma unroll
    for (int ks = 0; ks < 16; ++ks) sum += p_part[ks * 32 + dd * 16 + bb];
    a.out[(size_t)(ROWS * g + bb) * (T_OUT * D_OUT) + (size_t)95 * D_OUT + dd] = sum;
  }
}

extern "C" void kernel_launch(void* const* d_in, const int* in_sizes, int n_in,
                              void* d_out, int out_size, void* d_ws, size_t ws_size,
                              hipStream_t stream) {
  (void)in_sizes; (void)n_in; (void)out_size; (void)ws_size;
  const float* src   = (const float*)d_in[0];
  const float* eWih0 = (const float*)d_in[1];
  const float* eWhh0 = (const float*)d_in[2];
  const float* eb0   = (const float*)d_in[3];
  const float* eWih1 = (const float*)d_in[4];
  const float* eWhh1 = (const float*)d_in[5];
  const float* eb1   = (const float*)d_in[6];
  const float* dWih0 = (const float*)d_in[7];
  const float* dWhh0 = (const float*)d_in[8];
  const float* db0   = (const float*)d_in[9];
  const float* dWih1 = (const float*)d_in[10];
  const float* dWhh1 = (const float*)d_in[11];
  const float* db1   = (const float*)d_in[12];
  const float* fcW   = (const float*)d_in[13];
  const float* fcb   = (const float*)d_in[14];
  const float* pW    = (const float*)d_in[15];
  const float* pb    = (const float*)d_in[16];

  unsigned char* ws = (unsigned char*)d_ws;
  unsigned* cnt = (unsigned*)ws;                       // 4 KB
  unsigned short* W = (unsigned short*)(ws + 4096);    // 12.6 MB fp16 weights
  unsigned short* Hst = W + W_TOTAL;                   // 1 MB fp16 h-state

  (void)hipMemsetAsync(d_ws, 0, 4096, stream);
  (void)hipMemsetAsync((void*)Hst, 0, (size_t)4 * HBUF * sizeof(unsigned short), stream);

  hipLaunchKernelGGL(conv_kernel, dim3(W_TOTAL / 256), dim3(256), 0, stream,
                     eWhh0, eWih1, eWhh1, dWhh0, dWih1, dWhh1, W);

  Args a;
  a.src = src; a.eWih0 = eWih0; a.eb0 = eb0; a.eb1 = eb1;
  a.dWih0 = dWih0; a.db0 = db0; a.db1 = db1;
  a.fcW = fcW; a.fcb = fcb; a.pW = pW; a.pb = pb;
  a.W = W; a.Hst = Hst; a.out = (float*)d_out; a.cnt = cnt;

  // LDS: 32768 (HC) + (2176+2176+512+32+144+1024+256)*4 = 58048 B
  const size_t smem_bytes = (size_t)ROWS * HROW + (2176 + 2176 + 512 + 32 + 144 + 1024 + 256) * sizeof(float);
  hipLaunchKernelGGL(forecast_kernel, dim3(NGRP * WPG), dim3(NT), smem_bytes, stream, a);
}

// Round 7
// 5671.322 us; speedup vs baseline: 10.3407x; 1.2966x over previous
//
#include <hip/hip_runtime.h>
#include <hip/hip_fp16.h>
#include <math.h>

#define F 8
#define T_IN 336
#define T_OUT 96
#define D_OUT 2
#define NGRP 16
#define WPG 32
#define ROWS 16
#define NT 512
#define HROW 2048    // LDS hcat row stride bytes

// weight regions (shorts), kb-major tiled: [(s*4+w)][kb][lane(64)][8]
#define WE0 0
#define WE1 1048576
#define WD0 3145728
#define WD1 4194304
#define W_TOTAL 6291456
#define HO0 0
#define HO1 262144
#define HBUF 131072

using f32x4 = __attribute__((ext_vector_type(4))) float;
using f16x8 = __attribute__((ext_vector_type(8))) _Float16;

struct Args {
  const float *src;
  const float *eWih0, *eb0, *eb1;
  const float *dWih0, *db0, *db1;
  const float *fcW, *fcb, *pW, *pb;
  const unsigned short *W;
  unsigned short *Hst;
  float *out;
  unsigned *cnt;
};

__device__ __forceinline__ float sigm(float x) { return 1.f / (1.f + __expf(-x)); }
__device__ __forceinline__ float tanh_f(float x) {
  float e = __expf(-2.f * fabsf(x));
  float r = (1.f - e) / (1.f + e);
  return copysignf(r, x);
}
__device__ __forceinline__ f32x4 mfma16(f16x8 a, f16x8 b, f32x4 c) {
  return __builtin_amdgcn_mfma_f32_16x16x32_f16(a, b, c, 0, 0, 0);
}
__device__ __forceinline__ void ld16_cg(uint4& d, const void* p) {
  asm volatile("global_load_dwordx4 %0, %1, off sc0 sc1" : "=v"(d) : "v"(p));
}
__device__ __forceinline__ void st2_cg(void* p, unsigned v) {
  asm volatile("global_store_short %0, %1, off sc0 sc1" :: "v"(p), "v"(v) : "memory");
}

__device__ __forceinline__ void gbar(unsigned* cnt, unsigned& bar) {
  bar += WPG;
  asm volatile("s_waitcnt vmcnt(0)" ::: "memory");
  __syncthreads();
  if (threadIdx.x == 0) {
    __hip_atomic_fetch_add(cnt, 1u, __ATOMIC_RELAXED, __HIP_MEMORY_SCOPE_AGENT);
    long guard = 0;
    while (__hip_atomic_load(cnt, __ATOMIC_RELAXED, __HIP_MEMORY_SCOPE_AGENT) < bar) {
      __builtin_amdgcn_s_sleep(1);
      if (++guard > (1L << 22)) break;
    }
  }
  __syncthreads();
  asm volatile("" ::: "memory");
}

// fp32 -> fp16, kb-major wave-fragment layout:
// dst[i], i = ((s*4+w)*NKB + kb)*512 + lane*8 + e
// src row n = (c&3)*512 + 16*s + 4*w + (c>>2), c = lane&15; k = kb*32 + (lane>>4)*8 + e
__global__ __launch_bounds__(256) void conv_kernel(
    const float* eWhh0, const float* eWih1, const float* eWhh1,
    const float* dWhh0, const float* dWih1, const float* dWhh1,
    unsigned short* W) {
  size_t i = (size_t)blockIdx.x * 256 + threadIdx.x;
  if (i >= W_TOTAL) return;
  int set, j;
  if (i < WE1)      { set = 0; j = (int)i; }
  else if (i < WD0) { set = 1; j = (int)(i - WE1); }
  else if (i < WD1) { set = 2; j = (int)(i - WD0); }
  else              { set = 3; j = (int)(i - WD1); }
  const int big = (set == 1 || set == 3);        // K=1024 sets
  const int e = j & 7, lane = (j >> 3) & 63, r = j >> 9;
  const int kb = big ? (r & 31) : (r & 15);
  const int sw = big ? (r >> 5) : (r >> 4);
  const int s = sw >> 2, w = sw & 3;
  const int c = lane & 15;
  const int n = (c & 3) * 512 + 16 * s + 4 * w + (c >> 2);
  const int k = kb * 32 + (lane >> 4) * 8 + e;
  float v;
  if (set == 0)      v = eWhh0[(size_t)n * 512 + k];
  else if (set == 1) v = (k < 512) ? eWih1[(size_t)n * 512 + k] : eWhh1[(size_t)n * 512 + k - 512];
  else if (set == 2) v = dWhh0[(size_t)n * 512 + k];
  else               v = (k < 512) ? dWih1[(size_t)n * 512 + k] : dWhh1[(size_t)n * 512 + k - 512];
  W[i] = __half_as_ushort(__float2half_rn(v));
}

__global__ __launch_bounds__(NT, 4) void forecast_kernel(Args a) {
  extern __shared__ char smem[];
  char* HC = smem;                           // [16][2048B] fp16 hcat, XOR-swizzled
  float* TT = (float*)(smem + ROWS * HROW);  // [8 waves][16 cols][18] transpose scratch
  float* p_lds = TT + 8 * 288;               // [32]
  float* x_lds = p_lds + 32;                 // [16][9]
  float* WxL = x_lds + 144;                  // [2 sets][64 rows][9]
  float* bL = WxL + 1152;                    // [4 sets][4 gates][16 units]
  float* pWb = bL + 256;                     // [0..15] pW, [16..23] pb, [24..25] fcb

  const int tid = threadIdx.x;
  const int g = blockIdx.x >> 5;
  const int s = blockIdx.x & 31;
  const int lane = tid & 63, wid = tid >> 6;
  const int bb = lane & 15;        // batch row (A/D frag) == weight col (B frag)
  const int lq = lane >> 4;
  const int isL0 = (wid < 4);
  const int w4 = isL0 ? wid : wid - 4;
  const int uu = lane >> 4;        // unit sub-index for updates
  const int unitL = w4 * 4 + uu;   // unit within slice (0..15)
  const int rowG = 16 * g + bb;
  unsigned* cnt = a.cnt + g * 32;
  unsigned bar = 0;
  float* TTw = TT + wid * 288;

  const int nkbE = isL0 ? 16 : 32;
  const unsigned short* wE = a.W + (isL0 ? WE0 : WE1) + (size_t)(s * 4 + w4) * nkbE * 512 + lane * 8;
  const unsigned short* wD = a.W + (isL0 ? WD0 : WD1) + (size_t)(s * 4 + w4) * nkbE * 512 + lane * 8;

  // preload x-weights (padded stride 9), biases, proj/fc constants
  for (int e = tid; e < 1152; e += NT) {
    int set = e / 576, e2 = e % 576, row = e2 / 9, k = e2 % 9;
    const float* sw = set ? a.dWih0 : a.eWih0;
    WxL[e] = (k < 8) ? sw[(size_t)((row >> 4) * 512 + 16 * s + (row & 15)) * 8 + k] : 0.f;
  }
  if (tid < 256) {
    int bs = tid >> 6, q = (tid >> 4) & 3, u2 = tid & 15;
    const float* sp = bs == 0 ? a.eb0 : bs == 1 ? a.eb1 : bs == 2 ? a.db0 : a.db1;
    bL[tid] = sp[q * 512 + 16 * s + u2];
  }
  if (tid < 16) pWb[tid] = a.pW[tid];
  else if (tid < 24) pWb[tid] = a.pb[tid - 16];
  else if (tid < 26) pWb[tid] = a.fcb[tid - 24];
  __syncthreads();

  float c01 = 0.f;   // cell state: c0 on L0 waves, c1 on L1 waves
  const int srow = tid >> 5, seg = tid & 31;
  const int wswz = (srow & 7) << 4;
  const int aswz = (bb & 7) << 4;

  // ================= encoder =================
  for (int t = 0; t <= T_IN; ++t) {
    const int buf = t & 1, nbuf = buf ^ 1;
    {
      const unsigned short* p0 = a.Hst + HO0 + (size_t)buf * HBUF + (size_t)(16 * g + srow) * 512 + seg * 8;
      const unsigned short* p1 = a.Hst + HO1 + (size_t)buf * HBUF + (size_t)(16 * g + srow) * 512 + seg * 8;
      uint4 q0, q1, q2, q3;
      ld16_cg(q0, p0); ld16_cg(q1, p0 + 256); ld16_cg(q2, p1); ld16_cg(q3, p1 + 256);
      asm volatile("s_waitcnt vmcnt(0)" ::: "memory");
      __builtin_amdgcn_sched_barrier(0);
      char* d = HC + srow * HROW + ((seg * 16) ^ wswz);
      *(uint4*)d = q0; *(uint4*)(d + 512) = q1;
      *(uint4*)(d + 1024) = q2; *(uint4*)(d + 1536) = q3;
    }
    __syncthreads();
    const bool active = isL0 ? (t < T_IN) : (t >= 1);
    if (active) {
      f32x4 acc = {0.f, 0.f, 0.f, 0.f};
      const char* arow = HC + bb * HROW;
      for (int kb = 0; kb < nkbE; ++kb)
        acc = mfma16(*(const f16x8*)(arow + ((lq * 16 + kb * 64) ^ aswz)),
                     *(const f16x8*)(wE + (size_t)kb * 512), acc);
      #pragma unroll
      for (int j = 0; j < 4; ++j) TTw[bb * 18 + lq * 4 + j] = acc[j];   // col=bb, row=lq*4+j
      float ac[4];
      #pragma unroll
      for (int q = 0; q < 4; ++q)
        ac[q] = TTw[(4 * uu + q) * 18 + bb] + bL[(isL0 ? 0 : 64) + q * 16 + unitL];
      if (isL0) {
        const float* xr = a.src + (size_t)rowG * (T_IN * F) + t * F;
        float4 x0 = *(const float4*)xr, x1 = *(const float4*)(xr + 4);
        float xv[8] = {x0.x, x0.y, x0.z, x0.w, x1.x, x1.y, x1.z, x1.w};
        #pragma unroll
        for (int q = 0; q < 4; ++q)
          #pragma unroll
          for (int k = 0; k < 8; ++k)
            ac[q] = fmaf(xv[k], WxL[(q * 16 + unitL) * 9 + k], ac[q]);
      }
      c01 = sigm(ac[1]) * c01 + sigm(ac[0]) * tanh_f(ac[2]);
      float h = sigm(ac[3]) * tanh_f(c01);
      size_t idx = (size_t)nbuf * HBUF + (size_t)rowG * 512 + 16 * s + unitL;
      st2_cg((void*)(a.Hst + (isL0 ? HO0 : HO1) + idx),
             (unsigned)__half_as_ushort(__float2half_rn(h)));
    }
    gbar(cnt, bar);
  }

  // ================= decoder =================
  for (int t = 0; t < T_OUT; ++t) {
    const int pA = t & 1;
    {  // stage h0(t-1), h1(t-1)
      const unsigned short* p0 = a.Hst + HO0 + (size_t)pA * HBUF + (size_t)(16 * g + srow) * 512 + seg * 8;
      const unsigned short* p1 = a.Hst + HO1 + (size_t)(pA ^ 1) * HBUF + (size_t)(16 * g + srow) * 512 + seg * 8;
      uint4 q0, q1, q2, q3;
      ld16_cg(q0, p0); ld16_cg(q1, p0 + 256); ld16_cg(q2, p1); ld16_cg(q3, p1 + 256);
      asm volatile("s_waitcnt vmcnt(0)" ::: "memory");
      __builtin_amdgcn_sched_barrier(0);
      char* d = HC + srow * HROW + ((seg * 16) ^ wswz);
      *(uint4*)d = q0; *(uint4*)(d + 512) = q1;
      *(uint4*)(d + 1024) = q2; *(uint4*)(d + 1536) = q3;
    }
    __syncthreads();
    if (isL0) {  // D0 gate MFMAs
      f32x4 acc = {0.f, 0.f, 0.f, 0.f};
      const char* arow = HC + bb * HROW;
      for (int kb = 0; kb < 16; ++kb)
        acc = mfma16(*(const f16x8*)(arow + ((lq * 16 + kb * 64) ^ aswz)),
                     *(const f16x8*)(wD + (size_t)kb * 512), acc);
      #pragma unroll
      for (int j = 0; j < 4; ++j) TTw[bb * 18 + lq * 4 + j] = acc[j];
    } else if (wid == 4) {  // pred(t-1) + x(t), wave-local
      const int pb_ = lane & 15, dd = (lane >> 4) & 1, hf = lane >> 5;
      const char* hp = HC + pb_ * HROW;
      const float* wr = a.fcW + dd * 512 + hf * 256;
      float r = 0.f;
      #pragma unroll 8
      for (int j = 0; j < 32; ++j) {
        f16x8 v = *(const f16x8*)(hp + ((1024 + hf * 512 + j * 16) ^ ((pb_ & 7) << 4)));
        float4 w0 = *(const float4*)(wr + j * 8);
        float4 w1 = *(const float4*)(wr + j * 8 + 4);
        r = fmaf((float)v[0], w0.x, r); r = fmaf((float)v[1], w0.y, r);
        r = fmaf((float)v[2], w0.z, r); r = fmaf((float)v[3], w0.w, r);
        r = fmaf((float)v[4], w1.x, r); r = fmaf((float)v[5], w1.y, r);
        r = fmaf((float)v[6], w1.z, r); r = fmaf((float)v[7], w1.w, r);
      }
      r += __shfl_xor(r, 32);
      if (lane < 32) {
        float pred = r + pWb[24 + dd];
        if (t == 0) pred = a.src[(size_t)(16 * g + pb_) * (T_IN * F) + 335 * F + dd * 2];
        p_lds[pb_ * 2 + dd] = pred;
        if (s == 0 && t > 0)
          a.out[(size_t)(16 * g + pb_) * (T_OUT * D_OUT) + (size_t)(t - 1) * D_OUT + dd] = pred;
      }
      const int bx = lane >> 2, j0 = (lane & 3) * 2;
      float pr0 = p_lds[bx * 2], pr1 = p_lds[bx * 2 + 1];
      x_lds[bx * 9 + j0]     = pWb[16 + j0]     + pr0 * pWb[j0 * 2]       + pr1 * pWb[j0 * 2 + 1];
      x_lds[bx * 9 + j0 + 1] = pWb[16 + j0 + 1] + pr0 * pWb[(j0 + 1) * 2] + pr1 * pWb[(j0 + 1) * 2 + 1];
    }
    __syncthreads();
    if (isL0) {  // c0 update with x
      float ac[4];
      #pragma unroll
      for (int q = 0; q < 4; ++q)
        ac[q] = TTw[(4 * uu + q) * 18 + bb] + bL[128 + q * 16 + unitL];
      #pragma unroll
      for (int q = 0; q < 4; ++q)
        #pragma unroll
        for (int k = 0; k < 8; ++k)
          ac[q] = fmaf(x_lds[bb * 9 + k], WxL[576 + (q * 16 + unitL) * 9 + k], ac[q]);
      c01 = sigm(ac[1]) * c01 + sigm(ac[0]) * tanh_f(ac[2]);
      float h = sigm(ac[3]) * tanh_f(c01);
      size_t idx = (size_t)(pA ^ 1) * HBUF + (size_t)rowG * 512 + 16 * s + unitL;
      st2_cg((void*)(a.Hst + HO0 + idx), (unsigned)__half_as_ushort(__float2half_rn(h)));
    }
    gbar(cnt, bar);
    {  // stage h0(t)
      const unsigned short* p0 = a.Hst + HO0 + (size_t)(pA ^ 1) * HBUF + (size_t)(16 * g + srow) * 512 + seg * 8;
      uint4 q0, q1;
      ld16_cg(q0, p0); ld16_cg(q1, p0 + 256);
      asm volatile("s_waitcnt vmcnt(0)" ::: "memory");
      __builtin_amdgcn_sched_barrier(0);
      char* d = HC + srow * HROW + ((seg * 16) ^ wswz);
      *(uint4*)d = q0; *(uint4*)(d + 512) = q1;
    }
    __syncthreads();
    if (!isL0) {  // D1 gates + c1 update
      f32x4 acc = {0.f, 0.f, 0.f, 0.f};
      const char* arow = HC + bb * HROW;
      for (int kb = 0; kb < 32; ++kb)
        acc = mfma16(*(const f16x8*)(arow + ((lq * 16 + kb * 64) ^ aswz)),
                     *(const f16x8*)(wD + (size_t)kb * 512), acc);
      #pragma unroll
      for (int j = 0; j < 4; ++j) TTw[bb * 18 + lq * 4 + j] = acc[j];
      float ac[4];
      #pragma unroll
      for (int q = 0; q < 4; ++q)
        ac[q] = TTw[(4 * uu + q) * 18 + bb] + bL[192 + q * 16 + unitL];
      c01 = sigm(ac[1]) * c01 + sigm(ac[0]) * tanh_f(ac[2]);
      float h = sigm(ac[3]) * tanh_f(c01);
      size_t idx = (size_t)pA * HBUF + (size_t)rowG * 512 + 16 * s + unitL;
      st2_cg((void*)(a.Hst + HO1 + idx), (unsigned)__half_as_ushort(__float2half_rn(h)));
    }
    gbar(cnt, bar);
  }

  // ================= epilogue: pred(95) =================
  {
    const unsigned short* p1 = a.Hst + HO1 + (size_t)1 * HBUF + (size_t)(16 * g + srow) * 512 + seg * 8;
    uint4 q0, q1;
    ld16_cg(q0, p1); ld16_cg(q1, p1 + 256);
    asm volatile("s_waitcnt vmcnt(0)" ::: "memory");
    __builtin_amdgcn_sched_barrier(0);
    char* d = HC + srow * HROW + ((seg * 16) ^ wswz);
    *(uint4*)(d + 1024) = q0; *(uint4*)(d + 1536) = q1;
  }
  __syncthreads();
  if (wid == 4 && s == 0) {
    const int pb_ = lane & 15, dd = (lane >> 4) & 1, hf = lane >> 5;
    const char* hp = HC + pb_ * HROW;
    const float* wr = a.fcW + dd * 512 + hf * 256;
    float r = 0.f;
    #pragma unroll 8
    for (int j = 0; j < 32; ++j) {
      f16x8 v = *(const f16x8*)(hp + ((1024 + hf * 512 + j * 16) ^ ((pb_ & 7) << 4)));
      float4 w0 = *(const float4*)(wr + j * 8);
      float4 w1 = *(const float4*)(wr + j * 8 + 4);
      r = fmaf((float)v[0], w0.x, r); r = fmaf((float)v[1], w0.y, r);
      r = fmaf((float)v[2], w0.z, r); r = fmaf((float)v[3], w0.w, r);
      r = fmaf((float)v[4], w1.x, r); r = fmaf((float)v[5], w1.y, r);
      r = fmaf((float)v[6], w1.z, r); r = fmaf((float)v[7], w1.w, r);
    }
    r += __shfl_xor(r, 32);
    if (lane < 32)
      a.out[(size_t)(16 * g + pb_) * (T_OUT * D_OUT) + (size_t)95 * D_OUT + dd] = r + pWb[24 + dd];
  }
}

extern "C" void kernel_launch(void* const* d_in, const int* in_sizes, int n_in,
                              void* d_out, int out_size, void* d_ws, size_t ws_size,
                              hipStream_t stream) {
  (void)in_sizes; (void)n_in; (void)out_size; (void)ws_size;
  const float* src   = (const float*)d_in[0];
  const float* eWih0 = (const float*)d_in[1];
  const float* eWhh0 = (const float*)d_in[2];
  const float* eb0   = (const float*)d_in[3];
  const float* eWih1 = (const float*)d_in[4];
  const float* eWhh1 = (const float*)d_in[5];
  const float* eb1   = (const float*)d_in[6];
  const float* dWih0 = (const float*)d_in[7];
  const float* dWhh0 = (const float*)d_in[8];
  const float* db0   = (const float*)d_in[9];
  const float* dWih1 = (const float*)d_in[10];
  const float* dWhh1 = (const float*)d_in[11];
  const float* db1   = (const float*)d_in[12];
  const float* fcW   = (const float*)d_in[13];
  const float* fcb   = (const float*)d_in[14];
  const float* pW    = (const float*)d_in[15];
  const float* pb    = (const float*)d_in[16];

  unsigned char* ws = (unsigned char*)d_ws;
  unsigned* cnt = (unsigned*)ws;                       // 4 KB
  unsigned short* W = (unsigned short*)(ws + 4096);    // 12.6 MB fp16 tiled weights
  unsigned short* Hst = W + W_TOTAL;                   // 1 MB fp16 h-state

  (void)hipMemsetAsync(d_ws, 0, 4096, stream);
  (void)hipMemsetAsync((void*)Hst, 0, (size_t)4 * HBUF * sizeof(unsigned short), stream);

  hipLaunchKernelGGL(conv_kernel, dim3(W_TOTAL / 256), dim3(256), 0, stream,
                     eWhh0, eWih1, eWhh1, dWhh0, dWih1, dWhh1, W);

  Args a;
  a.src = src; a.eWih0 = eWih0; a.eb0 = eb0; a.eb1 = eb1;
  a.dWih0 = dWih0; a.db0 = db0; a.db1 = db1;
  a.fcW = fcW; a.fcb = fcb; a.pW = pW; a.pb = pb;
  a.W = W; a.Hst = Hst; a.out = (float*)d_out; a.cnt = cnt;

  // LDS: 32768 (HC) + 4*(2304 + 32 + 144 + 1152 + 256 + 32) = 48448 B
  const size_t smem_bytes = (size_t)ROWS * HROW + (2304 + 32 + 144 + 1152 + 256 + 32) * sizeof(float);
  hipLaunchKernelGGL(forecast_kernel, dim3(NGRP * WPG), dim3(NT), smem_bytes, stream, a);
}